// Round 10
// baseline (442.081 us; speedup 1.0000x reference)
//
#include <hip/hip_runtime.h>

#define N_NODES_C 40000
#define N_EDGES_C 640000
#define DIM 128
#define NB 50
#define LDA 132       // f32 transpose-buffer leading dim (528B rows: 16B-aligned)
#define BLK 256
#define TROWS 64      // fallback/node tile
#define EROWS 128     // edge kernel tile (2 row-tiles per wave)
#define LOG2_C 0.6931471805599453f
#define PI_OVER_CUT 0.6283185307179586f  // pi/5
#define NSCAN_BLK 157  // ceil(40000/256)

typedef __attribute__((ext_vector_type(8))) short s8v;   // 8 bf16 = A/B frag of 16x16x32
typedef __attribute__((ext_vector_type(4))) float f4v;   // C/D frag

#define MFMA_BF16 __builtin_amdgcn_mfma_f32_16x16x32_bf16

// Wsplit segment offsets (ushort units). Layout per weight: [nc][128 col][40], k at col*40+k.
#define SEG_IN2F_H 0
#define SEG_IN2F_L 20480
#define SEG_F1_H   40960
#define SEG_F1_L   51200
#define SEG_F2_H   61440
#define SEG_F2_L   81920
#define SEG_OUT_H  102400
#define SEG_OUT_L  122880
#define SEG_LIN_H  143360
#define SEG_LIN_L  163840
#define WSPLIT_USHORTS 184320

__device__ __forceinline__ unsigned short f2bf(float x) {   // RNE (pre-split kernel only)
    unsigned int u = __float_as_uint(x);
    u += 0x7fffu + ((u >> 16) & 1u);
    return (unsigned short)(u >> 16);
}
__device__ __forceinline__ float bf2f(unsigned short h) {
    return __uint_as_float(((unsigned int)h) << 16);
}
__device__ __forceinline__ float ssp_f(float t) {
    float e = __expf(-fabsf(t));
    return fmaxf(t, 0.0f) + __logf(1.0f + e) - LOG2_C;
}
// truncation split of 8 f32 -> bf16 hi/lo frags (residual exact)
__device__ __forceinline__ void split8t(const float* av, s8v& Ah, s8v& Al) {
#pragma unroll
    for (int j = 0; j < 8; j += 2) {
        unsigned int u0 = __float_as_uint(av[j]);
        unsigned int u1 = __float_as_uint(av[j + 1]);
        float h0 = __uint_as_float(u0 & 0xffff0000u);
        float h1 = __uint_as_float(u1 & 0xffff0000u);
        unsigned int r0 = __float_as_uint(av[j] - h0);
        unsigned int r1 = __float_as_uint(av[j + 1] - h1);
        ((unsigned int*)&Ah)[j >> 1] = __builtin_amdgcn_perm(u1, u0, 0x07060302);
        ((unsigned int*)&Al)[j >> 1] = __builtin_amdgcn_perm(r1, r0, 0x07060302);
    }
}
// single A-pair version (node kernels)
__device__ __forceinline__ void mfma8(const unsigned short* __restrict__ bh,
                                      const unsigned short* __restrict__ bl,
                                      const s8v& Ah, const s8v& Al, f4v acc[8]) {
    s8v B[8];
#pragma unroll
    for (int t = 0; t < 8; ++t) B[t] = *(const s8v*)(bl + t * 640);
#pragma unroll
    for (int t = 0; t < 8; ++t) acc[t] = MFMA_BF16(Ah, B[t], acc[t], 0, 0, 0);
#pragma unroll
    for (int t = 0; t < 8; ++t) B[t] = *(const s8v*)(bh + t * 640);
#pragma unroll
    for (int t = 0; t < 8; ++t) {
        acc[t] = MFMA_BF16(Al, B[t], acc[t], 0, 0, 0);
        acc[t] = MFMA_BF16(Ah, B[t], acc[t], 0, 0, 0);
    }
}
// two A-pairs share one B batch (edge kernel: 2x MFMA per load)
__device__ __forceinline__ void mfma8x2(const unsigned short* __restrict__ bh,
                                        const unsigned short* __restrict__ bl,
                                        const s8v& Ah0, const s8v& Al0,
                                        const s8v& Ah1, const s8v& Al1,
                                        f4v acc0[8], f4v acc1[8]) {
    s8v B[8];
#pragma unroll
    for (int t = 0; t < 8; ++t) B[t] = *(const s8v*)(bl + t * 640);
#pragma unroll
    for (int t = 0; t < 8; ++t) {
        acc0[t] = MFMA_BF16(Ah0, B[t], acc0[t], 0, 0, 0);
        acc1[t] = MFMA_BF16(Ah1, B[t], acc1[t], 0, 0, 0);
    }
#pragma unroll
    for (int t = 0; t < 8; ++t) B[t] = *(const s8v*)(bh + t * 640);
#pragma unroll
    for (int t = 0; t < 8; ++t) {
        acc0[t] = MFMA_BF16(Al0, B[t], acc0[t], 0, 0, 0);
        acc0[t] = MFMA_BF16(Ah0, B[t], acc0[t], 0, 0, 0);
        acc1[t] = MFMA_BF16(Al1, B[t], acc1[t], 0, 0, 0);
        acc1[t] = MFMA_BF16(Ah1, B[t], acc1[t], 0, 0, 0);
    }
}

// ---------------- weight pre-split (once per launch) ----------------
__global__ __launch_bounds__(BLK) void split5_kernel(const float* __restrict__ Wa,
                                                     const float* __restrict__ Wb,
                                                     const float* __restrict__ Wc,
                                                     const float* __restrict__ Wd,
                                                     const float* __restrict__ We,
                                                     unsigned short* __restrict__ Ws) {
    int i = blockIdx.x * BLK + threadIdx.x;
    if (i >= 18 * 4096) return;
    int chunk = i >> 12, r = i & 4095, k = r & 31, col = r >> 5;
    const float* W; int Kr, ck, hb, lb;
    if (chunk < 4)       { W = Wa; Kr = 128; ck = chunk;      hb = SEG_IN2F_H; lb = SEG_IN2F_L; }
    else if (chunk < 6)  { W = Wb; Kr = 50;  ck = chunk - 4;  hb = SEG_F1_H;   lb = SEG_F1_L; }
    else if (chunk < 10) { W = Wc; Kr = 128; ck = chunk - 6;  hb = SEG_F2_H;   lb = SEG_F2_L; }
    else if (chunk < 14) { W = Wd; Kr = 128; ck = chunk - 10; hb = SEG_OUT_H;  lb = SEG_OUT_L; }
    else                 { W = We; Kr = 128; ck = chunk - 14; hb = SEG_LIN_H;  lb = SEG_LIN_L; }
    int krow = ck * 32 + k;
    float v = (krow < Kr) ? W[(size_t)krow * DIM + col] : 0.f;
    unsigned short h16 = f2bf(v);
    int o = ck * 5120 + col * 40 + k;
    Ws[hb + o] = h16;
    Ws[lb + o] = f2bf(v - bf2f(h16));
}

// ---------------- h = x @ W_in2f  (MFMA, no LDS) ----------------
__global__ __launch_bounds__(BLK, 4) void node_in2f_mfma(const float* __restrict__ x,
                                                         const unsigned short* __restrict__ Ws,
                                                         float* __restrict__ h) {
    const int tid = threadIdx.x;
    const int w = tid >> 6, l = tid & 63, lr = l & 15, lk = l >> 4;
    const int n0 = blockIdx.x * TROWS;
    const int rowA = 16 * w + lr;
    const float* xr = x + (size_t)(n0 + rowA) * DIM;

    f4v acc[8];
#pragma unroll
    for (int t = 0; t < 8; ++t) acc[t] = (f4v){0.f, 0.f, 0.f, 0.f};
#pragma unroll
    for (int kc = 0; kc < 4; ++kc) {
        const float* ap = xr + kc * 32 + lk * 8;
        float4 a0 = *(const float4*)ap, a1 = *(const float4*)(ap + 4);
        float av[8] = {a0.x, a0.y, a0.z, a0.w, a1.x, a1.y, a1.z, a1.w};
        s8v Ah, Al; split8t(av, Ah, Al);
        const int bo = kc * 5120 + lr * 40 + lk * 8;
        mfma8(Ws + SEG_IN2F_H + bo, Ws + SEG_IN2F_L + bo, Ah, Al, acc);
    }
#pragma unroll
    for (int t = 0; t < 8; ++t)
#pragma unroll
        for (int r = 0; r < 4; ++r)
            h[(size_t)(n0 + 16 * w + lk * 4 + r) * DIM + t * 16 + lr] = acc[t][r];
}

// ---------------- CSR build ----------------
__global__ __launch_bounds__(BLK) void hist_kernel(const int* __restrict__ ind_i,
                                                   int* __restrict__ cnt) {
    int e = blockIdx.x * BLK + threadIdx.x;
    if (e < N_EDGES_C) atomicAdd(&cnt[ind_i[e]], 1);
}

__global__ __launch_bounds__(BLK) void scan1_kernel(const int* __restrict__ cnt,
                                                    int* __restrict__ excl,
                                                    int* __restrict__ bsum) {
    __shared__ int s[BLK];
    const int tid = threadIdx.x;
    const int idx = blockIdx.x * BLK + tid;
    int v = (idx < N_NODES_C) ? cnt[idx] : 0;
    s[tid] = v;
    __syncthreads();
    for (int off = 1; off < BLK; off <<= 1) {
        int t = (tid >= off) ? s[tid - off] : 0;
        __syncthreads();
        s[tid] += t;
        __syncthreads();
    }
    if (idx < N_NODES_C) excl[idx] = s[tid] - v;
    if (tid == BLK - 1) bsum[blockIdx.x] = s[tid];
}

__global__ __launch_bounds__(BLK) void scan2_kernel(int* __restrict__ bsum) {
    __shared__ int s[BLK];
    const int tid = threadIdx.x;
    int v = (tid < NSCAN_BLK) ? bsum[tid] : 0;
    s[tid] = v;
    __syncthreads();
    for (int off = 1; off < BLK; off <<= 1) {
        int t = (tid >= off) ? s[tid - off] : 0;
        __syncthreads();
        s[tid] += t;
        __syncthreads();
    }
    if (tid < NSCAN_BLK) bsum[tid] = s[tid] - v;  // exclusive
}

__global__ __launch_bounds__(BLK) void scan3_kernel(int* __restrict__ start,
                                                    int* __restrict__ cursor,
                                                    const int* __restrict__ bsum) {
    const int idx = blockIdx.x * BLK + threadIdx.x;
    if (idx < N_NODES_C) {
        int v = start[idx] + bsum[blockIdx.x];
        start[idx] = v;
        cursor[idx] = v;
    }
}

// place: also writes pos[e] = slot so the edge kernel can write msg in CSR order
__global__ __launch_bounds__(BLK) void place_kernel(const int* __restrict__ ind_i,
                                                    int* __restrict__ cursor,
                                                    int* __restrict__ pos) {
    int e = blockIdx.x * BLK + threadIdx.x;
    if (e < N_EDGES_C) {
        int slot = atomicAdd(&cursor[ind_i[e]], 1);
        pos[e] = slot;
    }
}

// ---------------- Edge kernel: 128 edges/block, 2 row-tiles per wave ----------------
// LDS (69632B): t1h[128][136] + t1l[128][136] ushort; alias tf f32[128][132] post-GEMM2.
__global__ __launch_bounds__(BLK, 2) void edge_kernel_mfma(const float* __restrict__ f_ij,
                                                           const float* __restrict__ r_ij,
                                                           const int* __restrict__ ind_j,
                                                           const int* __restrict__ pos,
                                                           const unsigned short* __restrict__ Ws,
                                                           const float* __restrict__ b_f1,
                                                           const float* __restrict__ b_f2,
                                                           const float* __restrict__ h,
                                                           float* __restrict__ msg) {
    __shared__ __align__(16) char smem[69632];
    unsigned short* t1h = (unsigned short*)smem;          // [128][136]
    unsigned short* t1l = t1h + 128 * 136;
    float* tf = (float*)smem;                             // [128][132] alias (post-GEMM2)

    const int tid = threadIdx.x;
    const int w = tid >> 6, l = tid & 63, lr = l & 15, lk = l >> 4;
    const int rt = tid >> 4, ct = tid & 15;
    const int e0 = blockIdx.x * EROWS;  // 640000 % 128 == 0
    const int rowA0 = 16 * w + lr;
    const int rowA1 = 64 + rowA0;

    // ---- GEMM1: t_pre = f @ W1 + b1 (2 row-tiles)
    f4v acc0[8], acc1[8];
#pragma unroll
    for (int t = 0; t < 8; ++t) {
        float bv = b_f1[t * 16 + lr];
        acc0[t] = (f4v){bv, bv, bv, bv};
        acc1[t] = (f4v){bv, bv, bv, bv};
    }
    const float* fr0 = f_ij + (size_t)(e0 + rowA0) * NB;
    const float* fr1 = f_ij + (size_t)(e0 + rowA1) * NB;
#pragma unroll
    for (int kc = 0; kc < 2; ++kc) {
        int kb = kc * 32 + lk * 8;
        float av0[8], av1[8];
#pragma unroll
        for (int ii = 0; ii < 4; ++ii) {
            int k = kb + ii * 2;                      // pairs never straddle 50 (even)
            float2 v0 = (k < NB) ? *(const float2*)(fr0 + k) : make_float2(0.f, 0.f);
            float2 v1 = (k < NB) ? *(const float2*)(fr1 + k) : make_float2(0.f, 0.f);
            av0[ii * 2] = v0.x; av0[ii * 2 + 1] = v0.y;
            av1[ii * 2] = v1.x; av1[ii * 2 + 1] = v1.y;
        }
        s8v Ah0, Al0, Ah1, Al1;
        split8t(av0, Ah0, Al0);
        split8t(av1, Ah1, Al1);
        const int bo = kc * 5120 + lr * 40 + lk * 8;
        mfma8x2(Ws + SEG_F1_H + bo, Ws + SEG_F1_L + bo, Ah0, Al0, Ah1, Al1, acc0, acc1);
    }
    // C1 (row 16w+lk*4+r [+64], col t*16+lr): ssp + split into t1h/t1l
#pragma unroll
    for (int t = 0; t < 8; ++t)
#pragma unroll
        for (int r = 0; r < 4; ++r) {
            {
                float v = ssp_f(acc0[t][r]);
                unsigned int u = __float_as_uint(v);
                float hf = __uint_as_float(u & 0xffff0000u);
                int idx = (16 * w + lk * 4 + r) * 136 + t * 16 + lr;
                t1h[idx] = (unsigned short)(u >> 16);
                t1l[idx] = (unsigned short)(__float_as_uint(v - hf) >> 16);
            }
            {
                float v = ssp_f(acc1[t][r]);
                unsigned int u = __float_as_uint(v);
                float hf = __uint_as_float(u & 0xffff0000u);
                int idx = (64 + 16 * w + lk * 4 + r) * 136 + t * 16 + lr;
                t1h[idx] = (unsigned short)(u >> 16);
                t1l[idx] = (unsigned short)(__float_as_uint(v - hf) >> 16);
            }
        }
    __syncthreads();

    // ---- GEMM2: msg_pre = t1 @ W2 + b2
#pragma unroll
    for (int t = 0; t < 8; ++t) {
        float bv = b_f2[t * 16 + lr];
        acc0[t] = (f4v){bv, bv, bv, bv};
        acc1[t] = (f4v){bv, bv, bv, bv};
    }
#pragma unroll
    for (int kc = 0; kc < 4; ++kc) {
        s8v Ah0 = *(const s8v*)&t1h[rowA0 * 136 + kc * 32 + lk * 8];
        s8v Al0 = *(const s8v*)&t1l[rowA0 * 136 + kc * 32 + lk * 8];
        s8v Ah1 = *(const s8v*)&t1h[rowA1 * 136 + kc * 32 + lk * 8];
        s8v Al1 = *(const s8v*)&t1l[rowA1 * 136 + kc * 32 + lk * 8];
        const int bo = kc * 5120 + lr * 40 + lk * 8;
        mfma8x2(Ws + SEG_F2_H + bo, Ws + SEG_F2_L + bo, Ah0, Al0, Ah1, Al1, acc0, acc1);
    }
    __syncthreads();   // all t1 reads done before tf overwrite
#pragma unroll
    for (int t = 0; t < 8; ++t)
#pragma unroll
        for (int r = 0; r < 4; ++r) {
            tf[(16 * w + lk * 4 + r) * LDA + t * 16 + lr] = acc0[t][r];
            tf[(64 + 16 * w + lk * 4 + r) * LDA + t * 16 + lr] = acc1[t][r];
        }
    __syncthreads();

    // ---- epilogue: cutoff, gather h[ind_j], write msg row at CSR slot pos[e]
#pragma unroll
    for (int half = 0; half < 2; ++half) {
#pragma unroll
        for (int i = 0; i < 4; ++i) {
            int row = half * 64 + rt * 4 + i;
            int e = e0 + row;
            float rr = r_ij[e];
            float C = (rr < 5.0f) ? (0.5f * __cosf(rr * PI_OVER_CUT) + 0.5f) : 0.0f;
            int nj = ind_j[e];
            const float* hp = &h[(size_t)nj * DIM + ct * 8];
            float4 h0 = *(const float4*)hp, h1 = *(const float4*)(hp + 4);
            const float* ep = &tf[row * LDA + ct * 8];
            float4 a0 = *(const float4*)ep, a1 = *(const float4*)(ep + 4);
            float* mp = &msg[(size_t)pos[e] * DIM + ct * 8];
            *(float4*)mp = make_float4(h0.x * a0.x * C, h0.y * a0.y * C,
                                       h0.z * a0.z * C, h0.w * a0.w * C);
            *(float4*)(mp + 4) = make_float4(h1.x * a1.x * C, h1.y * a1.y * C,
                                             h1.z * a1.z * C, h1.w * a1.w * C);
        }
    }
}

// ---------------- Gather: agg[n] = sum of contiguous CSR msg rows ----------------
__global__ __launch_bounds__(BLK) void gather_kernel(const float* __restrict__ msg,
                                                     const int* __restrict__ start,
                                                     const int* __restrict__ cnt,
                                                     float* __restrict__ agg) {
    const int wave = threadIdx.x >> 6;
    const int lane = threadIdx.x & 63;
    const int node = blockIdx.x * 4 + wave;
    if (node >= N_NODES_C) return;
    const int s = start[node];
    const int d = cnt[node];
    const float* base = msg + (size_t)s * DIM + lane * 2;
    float ax = 0.f, ay = 0.f;
    int k = 0;
    for (; k + 1 < d; k += 2) {
        float2 va = *(const float2*)(base + (size_t)k * DIM);
        float2 vb = *(const float2*)(base + (size_t)(k + 1) * DIM);
        ax += va.x + vb.x;
        ay += va.y + vb.y;
    }
    if (k < d) {
        float2 va = *(const float2*)(base + (size_t)k * DIM);
        ax += va.x;
        ay += va.y;
    }
    *(float2*)&agg[(size_t)node * DIM + lane * 2] = make_float2(ax, ay);
}

// ---------------- out = ssp(agg@W_out + b_out) @ W_lin + b_lin  (MFMA) ----------------
__global__ __launch_bounds__(BLK, 4) void node_out_mfma(const float* __restrict__ agg,
                                                        const unsigned short* __restrict__ Ws,
                                                        const float* __restrict__ b_out,
                                                        const float* __restrict__ b_lin,
                                                        float* __restrict__ out) {
    __shared__ __align__(16) char smem[34816];
    unsigned short* t1h = (unsigned short*)smem;
    unsigned short* t1l = t1h + 64 * 136;

    const int tid = threadIdx.x;
    const int w = tid >> 6, l = tid & 63, lr = l & 15, lk = l >> 4;
    const int n0 = blockIdx.x * TROWS;
    const int rowA = 16 * w + lr;
    const float* ar = agg + (size_t)(n0 + rowA) * DIM;

    f4v acc[8];
#pragma unroll
    for (int t = 0; t < 8; ++t) { float bv = b_out[t * 16 + lr]; acc[t] = (f4v){bv, bv, bv, bv}; }
#pragma unroll
    for (int kc = 0; kc < 4; ++kc) {
        const float* ap = ar + kc * 32 + lk * 8;
        float4 a0 = *(const float4*)ap, a1 = *(const float4*)(ap + 4);
        float av[8] = {a0.x, a0.y, a0.z, a0.w, a1.x, a1.y, a1.z, a1.w};
        s8v Ah, Al; split8t(av, Ah, Al);
        const int bo = kc * 5120 + lr * 40 + lk * 8;
        mfma8(Ws + SEG_OUT_H + bo, Ws + SEG_OUT_L + bo, Ah, Al, acc);
    }
#pragma unroll
    for (int t = 0; t < 8; ++t)
#pragma unroll
        for (int r = 0; r < 4; ++r) {
            float v = ssp_f(acc[t][r]);
            unsigned int u = __float_as_uint(v);
            float hf = __uint_as_float(u & 0xffff0000u);
            int idx = (16 * w + lk * 4 + r) * 136 + t * 16 + lr;
            t1h[idx] = (unsigned short)(u >> 16);
            t1l[idx] = (unsigned short)(__float_as_uint(v - hf) >> 16);
        }
    __syncthreads();

#pragma unroll
    for (int t = 0; t < 8; ++t) { float bv = b_lin[t * 16 + lr]; acc[t] = (f4v){bv, bv, bv, bv}; }
#pragma unroll
    for (int kc = 0; kc < 4; ++kc) {
        s8v Ah = *(const s8v*)&t1h[rowA * 136 + kc * 32 + lk * 8];
        s8v Al = *(const s8v*)&t1l[rowA * 136 + kc * 32 + lk * 8];
        const int bo = kc * 5120 + lr * 40 + lk * 8;
        mfma8(Ws + SEG_LIN_H + bo, Ws + SEG_LIN_L + bo, Ah, Al, acc);
    }
#pragma unroll
    for (int t = 0; t < 8; ++t)
#pragma unroll
        for (int r = 0; r < 4; ++r)
            out[(size_t)(n0 + 16 * w + lk * 4 + r) * DIM + t * 16 + lr] = acc[t][r];
}

// ================= vector fallback path (only if workspace too small) =================
__device__ __forceinline__ void stage_chunk(const float* __restrict__ B, int k0, int rows,
                                            float* __restrict__ Bc, int tid) {
    const int n4 = rows * (DIM / 4);
    const float4* Bg = (const float4*)B + (size_t)k0 * (DIM / 4);
    float4* Bc4 = (float4*)Bc;
    for (int i = tid; i < n4; i += BLK) Bc4[i] = Bg[i];
}

__device__ __forceinline__ void init_acc_bias(float acc[4][8], const float* __restrict__ b, int ct) {
    float4 bb0 = *(const float4*)&b[ct * 8];
    float4 bb1 = *(const float4*)&b[ct * 8 + 4];
#pragma unroll
    for (int i = 0; i < 4; ++i) {
        acc[i][0] = bb0.x; acc[i][1] = bb0.y; acc[i][2] = bb0.z; acc[i][3] = bb0.w;
        acc[i][4] = bb1.x; acc[i][5] = bb1.y; acc[i][6] = bb1.z; acc[i][7] = bb1.w;
    }
}

template <int KPAD>
__device__ __forceinline__ void gemm_tile(const float* __restrict__ A_lds, int lda,
                                          const float* __restrict__ Bglob,
                                          float* __restrict__ Bc,
                                          float acc[4][8], int rt, int ct, int tid) {
    for (int k0 = 0; k0 < KPAD; k0 += 32) {
        __syncthreads();
        stage_chunk(Bglob, k0, 32, Bc, tid);
        __syncthreads();
#pragma unroll 2
        for (int k4 = 0; k4 < 8; ++k4) {
            float4 av[4];
#pragma unroll
            for (int i = 0; i < 4; ++i)
                av[i] = *(const float4*)&A_lds[(rt * 4 + i) * lda + k0 + k4 * 4];
#pragma unroll
            for (int kk = 0; kk < 4; ++kk) {
                const float* bp = &Bc[(k4 * 4 + kk) * DIM + ct * 8];
                float4 b0 = *(const float4*)bp;
                float4 b1 = *(const float4*)(bp + 4);
#pragma unroll
                for (int i = 0; i < 4; ++i) {
                    float a = ((const float*)&av[i])[kk];
                    acc[i][0] = fmaf(a, b0.x, acc[i][0]);
                    acc[i][1] = fmaf(a, b0.y, acc[i][1]);
                    acc[i][2] = fmaf(a, b0.z, acc[i][2]);
                    acc[i][3] = fmaf(a, b0.w, acc[i][3]);
                    acc[i][4] = fmaf(a, b1.x, acc[i][4]);
                    acc[i][5] = fmaf(a, b1.y, acc[i][5]);
                    acc[i][6] = fmaf(a, b1.z, acc[i][6]);
                    acc[i][7] = fmaf(a, b1.w, acc[i][7]);
                }
            }
        }
    }
}

template <int NK2>
__device__ __forceinline__ void gemm1_direct(const float* const (&frow)[4], int k2base,
                                             const float* __restrict__ Bc,
                                             float acc[4][8], int ct) {
#pragma unroll 4
    for (int k2 = 0; k2 < NK2; ++k2) {
        float2 a2[4];
#pragma unroll
        for (int i = 0; i < 4; ++i)
            a2[i] = *(const float2*)(frow[i] + (k2base + k2) * 2);
#pragma unroll
        for (int kk = 0; kk < 2; ++kk) {
            const float* bp = &Bc[(k2 * 2 + kk) * DIM + ct * 8];
            float4 b0 = *(const float4*)bp;
            float4 b1 = *(const float4*)(bp + 4);
#pragma unroll
            for (int i = 0; i < 4; ++i) {
                float a = kk ? a2[i].y : a2[i].x;
                acc[i][0] = fmaf(a, b0.x, acc[i][0]);
                acc[i][1] = fmaf(a, b0.y, acc[i][1]);
                acc[i][2] = fmaf(a, b0.z, acc[i][2]);
                acc[i][3] = fmaf(a, b0.w, acc[i][3]);
                acc[i][4] = fmaf(a, b1.x, acc[i][4]);
                acc[i][5] = fmaf(a, b1.y, acc[i][5]);
                acc[i][6] = fmaf(a, b1.z, acc[i][6]);
                acc[i][7] = fmaf(a, b1.w, acc[i][7]);
            }
        }
    }
}

__global__ __launch_bounds__(BLK) void node_in2f_fb(const float* __restrict__ x,
                                                    const float* __restrict__ W,
                                                    float* __restrict__ h) {
    __shared__ float At[TROWS * LDA];
    __shared__ float Bc[32 * DIM];
    const int tid = threadIdx.x;
    const int rt = tid >> 4, ct = tid & 15;
    const int n0 = blockIdx.x * TROWS;
    for (int i = tid; i < TROWS * (DIM / 4); i += BLK) {
        int row = i >> 5, c4 = i & 31;
        *(float4*)&At[row * LDA + c4 * 4] = *(const float4*)&x[(size_t)(n0 + row) * DIM + c4 * 4];
    }
    float acc[4][8];
#pragma unroll
    for (int i = 0; i < 4; ++i)
#pragma unroll
        for (int j = 0; j < 8; ++j) acc[i][j] = 0.f;
    gemm_tile<DIM>(At, LDA, W, Bc, acc, rt, ct, tid);
#pragma unroll
    for (int i = 0; i < 4; ++i) {
        float* hp = &h[(size_t)(n0 + rt * 4 + i) * DIM + ct * 8];
        *(float4*)hp = make_float4(acc[i][0], acc[i][1], acc[i][2], acc[i][3]);
        *(float4*)(hp + 4) = make_float4(acc[i][4], acc[i][5], acc[i][6], acc[i][7]);
    }
}

__global__ __launch_bounds__(BLK) void node_out_fb(const float* __restrict__ agg,
                                                   const float* __restrict__ W_out,
                                                   const float* __restrict__ b_out,
                                                   const float* __restrict__ W_lin,
                                                   const float* __restrict__ b_lin,
                                                   float* __restrict__ out) {
    __shared__ float At[TROWS * LDA];
    __shared__ float Bc[32 * DIM];
    const int tid = threadIdx.x;
    const int rt = tid >> 4, ct = tid & 15;
    const int n0 = blockIdx.x * TROWS;
    for (int i = tid; i < TROWS * (DIM / 4); i += BLK) {
        int row = i >> 5, c4 = i & 31;
        *(float4*)&At[row * LDA + c4 * 4] = *(const float4*)&agg[(size_t)(n0 + row) * DIM + c4 * 4];
    }
    float acc[4][8];
    init_acc_bias(acc, b_out, ct);
    gemm_tile<DIM>(At, LDA, W_out, Bc, acc, rt, ct, tid);
    __syncthreads();
#pragma unroll
    for (int i = 0; i < 4; ++i) {
        float* tp = &At[(rt * 4 + i) * LDA + ct * 8];
        *(float4*)tp = make_float4(ssp_f(acc[i][0]), ssp_f(acc[i][1]),
                                   ssp_f(acc[i][2]), ssp_f(acc[i][3]));
        *(float4*)(tp + 4) = make_float4(ssp_f(acc[i][4]), ssp_f(acc[i][5]),
                                         ssp_f(acc[i][6]), ssp_f(acc[i][7]));
    }
    init_acc_bias(acc, b_lin, ct);
    gemm_tile<DIM>(At, LDA, W_lin, Bc, acc, rt, ct, tid);
#pragma unroll
    for (int i = 0; i < 4; ++i) {
        float* op = &out[(size_t)(n0 + rt * 4 + i) * DIM + ct * 8];
        *(float4*)op = make_float4(acc[i][0], acc[i][1], acc[i][2], acc[i][3]);
        *(float4*)(op + 4) = make_float4(acc[i][4], acc[i][5], acc[i][6], acc[i][7]);
    }
}

__global__ __launch_bounds__(BLK) void edge_kernel_atomic(const float* __restrict__ f_ij,
                                                          const float* __restrict__ r_ij,
                                                          const int* __restrict__ ind_i,
                                                          const int* __restrict__ ind_j,
                                                          const float* __restrict__ W_f1,
                                                          const float* __restrict__ b_f1,
                                                          const float* __restrict__ W_f2,
                                                          const float* __restrict__ b_f2,
                                                          const float* __restrict__ h,
                                                          float* __restrict__ agg) {
    __shared__ float t1[TROWS * LDA];
    __shared__ float Bc[32 * DIM];
    const int tid = threadIdx.x;
    const int rt = tid >> 4, ct = tid & 15;
    const int e0 = blockIdx.x * TROWS;
    const float* frow[4];
#pragma unroll
    for (int i = 0; i < 4; ++i) frow[i] = f_ij + (size_t)(e0 + rt * 4 + i) * NB;
    float acc[4][8];
    init_acc_bias(acc, b_f1, ct);
    stage_chunk(W_f1, 0, 32, Bc, tid);
    __syncthreads();
    gemm1_direct<16>(frow, 0, Bc, acc, ct);
    __syncthreads();
    stage_chunk(W_f1, 32, 18, Bc, tid);
    __syncthreads();
    gemm1_direct<9>(frow, 16, Bc, acc, ct);
#pragma unroll
    for (int i = 0; i < 4; ++i) {
        float* tp = &t1[(rt * 4 + i) * LDA + ct * 8];
        *(float4*)tp = make_float4(ssp_f(acc[i][0]), ssp_f(acc[i][1]),
                                   ssp_f(acc[i][2]), ssp_f(acc[i][3]));
        *(float4*)(tp + 4) = make_float4(ssp_f(acc[i][4]), ssp_f(acc[i][5]),
                                         ssp_f(acc[i][6]), ssp_f(acc[i][7]));
    }
    init_acc_bias(acc, b_f2, ct);
    gemm_tile<DIM>(t1, LDA, W_f2, Bc, acc, rt, ct, tid);
#pragma unroll
    for (int i = 0; i < 4; ++i) {
        int e = e0 + rt * 4 + i;
        float r = r_ij[e];
        float C = (r < 5.0f) ? 0.5f * (cosf(r * PI_OVER_CUT) + 1.0f) : 0.0f;
        int nj = ind_j[e];
        int ni = ind_i[e];
        const float* hp = &h[(size_t)nj * DIM + ct * 8];
        float4 h0 = *(const float4*)hp;
        float4 h1 = *(const float4*)(hp + 4);
        float* ap = &agg[(size_t)ni * DIM + ct * 8];
        atomicAdd(ap + 0, h0.x * acc[i][0] * C);
        atomicAdd(ap + 1, h0.y * acc[i][1] * C);
        atomicAdd(ap + 2, h0.z * acc[i][2] * C);
        atomicAdd(ap + 3, h0.w * acc[i][3] * C);
        atomicAdd(ap + 4, h1.x * acc[i][4] * C);
        atomicAdd(ap + 5, h1.y * acc[i][5] * C);
        atomicAdd(ap + 6, h1.z * acc[i][6] * C);
        atomicAdd(ap + 7, h1.w * acc[i][7] * C);
    }
}

extern "C" void kernel_launch(void* const* d_in, const int* in_sizes, int n_in,
                              void* d_out, int out_size, void* d_ws, size_t ws_size,
                              hipStream_t stream) {
    const float* x      = (const float*)d_in[0];
    const float* r_ij   = (const float*)d_in[1];
    const float* f_ij   = (const float*)d_in[2];
    const int*   ind_i  = (const int*)d_in[3];
    const int*   ind_j  = (const int*)d_in[4];
    const float* W_in2f = (const float*)d_in[5];
    const float* W_f1   = (const float*)d_in[6];
    const float* b_f1   = (const float*)d_in[7];
    const float* W_f2   = (const float*)d_in[8];
    const float* b_f2   = (const float*)d_in[9];
    const float* W_out  = (const float*)d_in[10];
    const float* b_out  = (const float*)d_in[11];
    const float* W_lin  = (const float*)d_in[12];
    const float* b_lin  = (const float*)d_in[13];
    float* out = (float*)d_out;

    char* ws = (char*)d_ws;
    size_t off = 0;
    auto alloc = [&](size_t bytes) {
        char* p = ws + off;
        off = (off + bytes + 511) & ~(size_t)511;
        return p;
    };
    unsigned short* Wsplit = (unsigned short*)alloc(WSPLIT_USHORTS * sizeof(unsigned short));
    float* h      = (float*)alloc((size_t)N_NODES_C * DIM * sizeof(float));
    float* agg    = (float*)alloc((size_t)N_NODES_C * DIM * sizeof(float));
    float* msg    = (float*)alloc((size_t)N_EDGES_C * DIM * sizeof(float));
    int*   pos    = (int*)alloc((size_t)N_EDGES_C * sizeof(int));
    int*   cnt    = (int*)alloc((size_t)N_NODES_C * sizeof(int));
    int*   startA = (int*)alloc((size_t)N_NODES_C * sizeof(int));
    int*   cursor = (int*)alloc((size_t)N_NODES_C * sizeof(int));
    int*   bsum   = (int*)alloc((size_t)NSCAN_BLK * sizeof(int));
    const bool have_ws = (off <= ws_size);

    if (have_ws) {
        split5_kernel<<<(18 * 4096 + BLK - 1) / BLK, BLK, 0, stream>>>(
            W_in2f, W_f1, W_f2, W_out, W_lin, Wsplit);

        node_in2f_mfma<<<N_NODES_C / TROWS, BLK, 0, stream>>>(x, Wsplit, h);

        hipMemsetAsync(cnt, 0, (size_t)N_NODES_C * sizeof(int), stream);
        hist_kernel<<<(N_EDGES_C + BLK - 1) / BLK, BLK, 0, stream>>>(ind_i, cnt);
        scan1_kernel<<<NSCAN_BLK, BLK, 0, stream>>>(cnt, startA, bsum);
        scan2_kernel<<<1, BLK, 0, stream>>>(bsum);
        scan3_kernel<<<NSCAN_BLK, BLK, 0, stream>>>(startA, cursor, bsum);
        place_kernel<<<(N_EDGES_C + BLK - 1) / BLK, BLK, 0, stream>>>(ind_i, cursor, pos);

        edge_kernel_mfma<<<N_EDGES_C / EROWS, BLK, 0, stream>>>(
            f_ij, r_ij, ind_j, pos, Wsplit, b_f1, b_f2, h, msg);
        gather_kernel<<<(N_NODES_C + 3) / 4, BLK, 0, stream>>>(msg, startA, cnt, agg);

        node_out_mfma<<<N_NODES_C / TROWS, BLK, 0, stream>>>(agg, Wsplit, b_out, b_lin, out);
    } else {
        // minimal-workspace vector fallback (h + agg only)
        float* h2   = (float*)d_ws;
        float* agg2 = h2 + (size_t)N_NODES_C * DIM;
        node_in2f_fb<<<N_NODES_C / TROWS, BLK, 0, stream>>>(x, W_in2f, h2);
        hipMemsetAsync(agg2, 0, (size_t)N_NODES_C * DIM * sizeof(float), stream);
        edge_kernel_atomic<<<N_EDGES_C / TROWS, BLK, 0, stream>>>(
            f_ij, r_ij, ind_i, ind_j, W_f1, b_f1, W_f2, b_f2, h2, agg2);
        node_out_fb<<<N_NODES_C / TROWS, BLK, 0, stream>>>(agg2, W_out, b_out, W_lin, b_lin, out);
    }
}

// Round 11
// 358.582 us; speedup vs baseline: 1.2329x; 1.2329x over previous
//
#include <hip/hip_runtime.h>
#include <hip/hip_fp16.h>

#define N_NODES_C 40000
#define N_EDGES_C 640000
#define DIM 128
#define NB 50
#define LDA 132       // f32 transpose-buffer leading dim (528B rows: 16B-aligned)
#define BLK 256
#define TROWS 64
#define LOG2_C 0.6931471805599453f
#define PI_OVER_CUT 0.6283185307179586f  // pi/5
#define NSCAN_BLK 157  // ceil(40000/256)

typedef __attribute__((ext_vector_type(8))) short s8v;   // 8 bf16 = A/B frag of 16x16x32
typedef __attribute__((ext_vector_type(4))) float f4v;   // C/D frag

#define MFMA_BF16 __builtin_amdgcn_mfma_f32_16x16x32_bf16

// Wsplit segment offsets (ushort units). Layout per weight: [nc][128 col][40], k at col*40+k.
#define SEG_IN2F_H 0
#define SEG_IN2F_L 20480
#define SEG_F1_H   40960
#define SEG_F1_L   51200
#define SEG_F2_H   61440
#define SEG_F2_L   81920
#define SEG_OUT_H  102400
#define SEG_OUT_L  122880
#define SEG_LIN_H  143360
#define SEG_LIN_L  163840
#define WSPLIT_USHORTS 184320

__device__ __forceinline__ unsigned short f2bf(float x) {   // RNE (pre-split kernel only)
    unsigned int u = __float_as_uint(x);
    u += 0x7fffu + ((u >> 16) & 1u);
    return (unsigned short)(u >> 16);
}
__device__ __forceinline__ float bf2f(unsigned short h) {
    return __uint_as_float(((unsigned int)h) << 16);
}
__device__ __forceinline__ float ssp_f(float t) {
    float e = __expf(-fabsf(t));
    return fmaxf(t, 0.0f) + __logf(1.0f + e) - LOG2_C;
}
// truncation split of 8 f32 -> bf16 hi/lo frags (residual exact)
__device__ __forceinline__ void split8t(const float* av, s8v& Ah, s8v& Al) {
#pragma unroll
    for (int j = 0; j < 8; j += 2) {
        unsigned int u0 = __float_as_uint(av[j]);
        unsigned int u1 = __float_as_uint(av[j + 1]);
        float h0 = __uint_as_float(u0 & 0xffff0000u);
        float h1 = __uint_as_float(u1 & 0xffff0000u);
        unsigned int r0 = __float_as_uint(av[j] - h0);
        unsigned int r1 = __float_as_uint(av[j + 1] - h1);
        ((unsigned int*)&Ah)[j >> 1] = __builtin_amdgcn_perm(u1, u0, 0x07060302);
        ((unsigned int*)&Al)[j >> 1] = __builtin_amdgcn_perm(r1, r0, 0x07060302);
    }
}
// 8 output tiles x 3-term split MFMA; B-frag loads batched 8-wide
__device__ __forceinline__ void mfma8(const unsigned short* __restrict__ bh,
                                      const unsigned short* __restrict__ bl,
                                      const s8v& Ah, const s8v& Al, f4v acc[8]) {
    s8v B[8];
#pragma unroll
    for (int t = 0; t < 8; ++t) B[t] = *(const s8v*)(bl + t * 640);
#pragma unroll
    for (int t = 0; t < 8; ++t) acc[t] = MFMA_BF16(Ah, B[t], acc[t], 0, 0, 0);
#pragma unroll
    for (int t = 0; t < 8; ++t) B[t] = *(const s8v*)(bh + t * 640);
#pragma unroll
    for (int t = 0; t < 8; ++t) {
        acc[t] = MFMA_BF16(Al, B[t], acc[t], 0, 0, 0);
        acc[t] = MFMA_BF16(Ah, B[t], acc[t], 0, 0, 0);
    }
}

// ---------------- weight pre-split (once per launch) ----------------
__global__ __launch_bounds__(BLK) void split5_kernel(const float* __restrict__ Wa,
                                                     const float* __restrict__ Wb,
                                                     const float* __restrict__ Wc,
                                                     const float* __restrict__ Wd,
                                                     const float* __restrict__ We,
                                                     unsigned short* __restrict__ Ws) {
    int i = blockIdx.x * BLK + threadIdx.x;
    if (i >= 18 * 4096) return;
    int chunk = i >> 12, r = i & 4095, k = r & 31, col = r >> 5;
    const float* W; int Kr, ck, hb, lb;
    if (chunk < 4)       { W = Wa; Kr = 128; ck = chunk;      hb = SEG_IN2F_H; lb = SEG_IN2F_L; }
    else if (chunk < 6)  { W = Wb; Kr = 50;  ck = chunk - 4;  hb = SEG_F1_H;   lb = SEG_F1_L; }
    else if (chunk < 10) { W = Wc; Kr = 128; ck = chunk - 6;  hb = SEG_F2_H;   lb = SEG_F2_L; }
    else if (chunk < 14) { W = Wd; Kr = 128; ck = chunk - 10; hb = SEG_OUT_H;  lb = SEG_OUT_L; }
    else                 { W = We; Kr = 128; ck = chunk - 14; hb = SEG_LIN_H;  lb = SEG_LIN_L; }
    int krow = ck * 32 + k;
    float v = (krow < Kr) ? W[(size_t)krow * DIM + col] : 0.f;
    unsigned short h16 = f2bf(v);
    int o = ck * 5120 + col * 40 + k;
    Ws[hb + o] = h16;
    Ws[lb + o] = f2bf(v - bf2f(h16));
}

// ---------------- h = x @ W_in2f  (MFMA, no LDS) ----------------
__global__ __launch_bounds__(BLK, 4) void node_in2f_mfma(const float* __restrict__ x,
                                                         const unsigned short* __restrict__ Ws,
                                                         float* __restrict__ h) {
    const int tid = threadIdx.x;
    const int w = tid >> 6, l = tid & 63, lr = l & 15, lk = l >> 4;
    const int n0 = blockIdx.x * TROWS;
    const int rowA = 16 * w + lr;
    const float* xr = x + (size_t)(n0 + rowA) * DIM;

    f4v acc[8];
#pragma unroll
    for (int t = 0; t < 8; ++t) acc[t] = (f4v){0.f, 0.f, 0.f, 0.f};
#pragma unroll
    for (int kc = 0; kc < 4; ++kc) {
        const float* ap = xr + kc * 32 + lk * 8;
        float4 a0 = *(const float4*)ap, a1 = *(const float4*)(ap + 4);
        float av[8] = {a0.x, a0.y, a0.z, a0.w, a1.x, a1.y, a1.z, a1.w};
        s8v Ah, Al; split8t(av, Ah, Al);
        const int bo = kc * 5120 + lr * 40 + lk * 8;
        mfma8(Ws + SEG_IN2F_H + bo, Ws + SEG_IN2F_L + bo, Ah, Al, acc);
    }
#pragma unroll
    for (int t = 0; t < 8; ++t)
#pragma unroll
        for (int r = 0; r < 4; ++r)
            h[(size_t)(n0 + 16 * w + lk * 4 + r) * DIM + t * 16 + lr] = acc[t][r];
}

// ---------------- CSR build ----------------
__global__ __launch_bounds__(BLK) void hist_kernel(const int* __restrict__ ind_i,
                                                   int* __restrict__ cnt) {
    int e = blockIdx.x * BLK + threadIdx.x;
    if (e < N_EDGES_C) atomicAdd(&cnt[ind_i[e]], 1);
}

__global__ __launch_bounds__(BLK) void scan1_kernel(const int* __restrict__ cnt,
                                                    int* __restrict__ excl,
                                                    int* __restrict__ bsum) {
    __shared__ int s[BLK];
    const int tid = threadIdx.x;
    const int idx = blockIdx.x * BLK + tid;
    int v = (idx < N_NODES_C) ? cnt[idx] : 0;
    s[tid] = v;
    __syncthreads();
    for (int off = 1; off < BLK; off <<= 1) {
        int t = (tid >= off) ? s[tid - off] : 0;
        __syncthreads();
        s[tid] += t;
        __syncthreads();
    }
    if (idx < N_NODES_C) excl[idx] = s[tid] - v;
    if (tid == BLK - 1) bsum[blockIdx.x] = s[tid];
}

__global__ __launch_bounds__(BLK) void scan2_kernel(int* __restrict__ bsum) {
    __shared__ int s[BLK];
    const int tid = threadIdx.x;
    int v = (tid < NSCAN_BLK) ? bsum[tid] : 0;
    s[tid] = v;
    __syncthreads();
    for (int off = 1; off < BLK; off <<= 1) {
        int t = (tid >= off) ? s[tid - off] : 0;
        __syncthreads();
        s[tid] += t;
        __syncthreads();
    }
    if (tid < NSCAN_BLK) bsum[tid] = s[tid] - v;  // exclusive
}

__global__ __launch_bounds__(BLK) void scan3_kernel(int* __restrict__ start,
                                                    int* __restrict__ cursor,
                                                    const int* __restrict__ bsum) {
    const int idx = blockIdx.x * BLK + threadIdx.x;
    if (idx < N_NODES_C) {
        int v = start[idx] + bsum[blockIdx.x];
        start[idx] = v;
        cursor[idx] = v;
    }
}

// place: writes pos[e] = CSR slot so the edge kernel writes msg in CSR order
__global__ __launch_bounds__(BLK) void place_kernel(const int* __restrict__ ind_i,
                                                    int* __restrict__ cursor,
                                                    int* __restrict__ pos) {
    int e = blockIdx.x * BLK + threadIdx.x;
    if (e < N_EDGES_C) {
        int slot = atomicAdd(&cursor[ind_i[e]], 1);
        pos[e] = slot;
    }
}

// ---------------- Edge kernel: full MFMA; t1 pre-split in LDS; msg in fp16 ----------------
// LDS (34816B): t1h[64][136] + t1l[64][136] ushort; alias tf f32[64][132] post-GEMM2.
__global__ __launch_bounds__(BLK, 4) void edge_kernel_mfma(const float* __restrict__ f_ij,
                                                           const float* __restrict__ r_ij,
                                                           const int* __restrict__ ind_j,
                                                           const int* __restrict__ pos,
                                                           const unsigned short* __restrict__ Ws,
                                                           const float* __restrict__ b_f1,
                                                           const float* __restrict__ b_f2,
                                                           const float* __restrict__ h,
                                                           __half* __restrict__ msg) {
    __shared__ __align__(16) char smem[34816];
    unsigned short* t1h = (unsigned short*)smem;          // [64][136]
    unsigned short* t1l = t1h + 64 * 136;
    float* tf = (float*)smem;                             // [64][132] alias (post-GEMM2)

    const int tid = threadIdx.x;
    const int w = tid >> 6, l = tid & 63, lr = l & 15, lk = l >> 4;
    const int rt = tid >> 4, ct = tid & 15;
    const int e0 = blockIdx.x * TROWS;  // 640000 % 64 == 0
    const int rowA = 16 * w + lr;

    // ---- GEMM1: t_pre = f @ W1 + b1; A in-reg from global f_ij (float2, 8B-aligned)
    f4v acc[8];
#pragma unroll
    for (int t = 0; t < 8; ++t) { float bv = b_f1[t * 16 + lr]; acc[t] = (f4v){bv, bv, bv, bv}; }
    const float* fr = f_ij + (size_t)(e0 + rowA) * NB;
#pragma unroll
    for (int kc = 0; kc < 2; ++kc) {
        int kb = kc * 32 + lk * 8;
        float av[8];
#pragma unroll
        for (int ii = 0; ii < 4; ++ii) {
            int k = kb + ii * 2;                      // pairs never straddle 50 (even)
            float2 v = (k < NB) ? *(const float2*)(fr + k) : make_float2(0.f, 0.f);
            av[ii * 2] = v.x; av[ii * 2 + 1] = v.y;
        }
        s8v Ah, Al; split8t(av, Ah, Al);
        const int bo = kc * 5120 + lr * 40 + lk * 8;
        mfma8(Ws + SEG_F1_H + bo, Ws + SEG_F1_L + bo, Ah, Al, acc);
    }
    // C1 (row 16w+lk*4+r, col t*16+lr): ssp + truncation-split into t1h/t1l
#pragma unroll
    for (int t = 0; t < 8; ++t)
#pragma unroll
        for (int r = 0; r < 4; ++r) {
            float v = ssp_f(acc[t][r]);
            unsigned int u = __float_as_uint(v);
            float hf = __uint_as_float(u & 0xffff0000u);
            int idx = (16 * w + lk * 4 + r) * 136 + t * 16 + lr;
            t1h[idx] = (unsigned short)(u >> 16);
            t1l[idx] = (unsigned short)(__float_as_uint(v - hf) >> 16);
        }
    __syncthreads();

    // ---- GEMM2: msg_pre = t1 @ W2 + b2; A-frags pre-split from LDS (b128)
#pragma unroll
    for (int t = 0; t < 8; ++t) { float bv = b_f2[t * 16 + lr]; acc[t] = (f4v){bv, bv, bv, bv}; }
#pragma unroll
    for (int kc = 0; kc < 4; ++kc) {
        s8v Ah = *(const s8v*)&t1h[rowA * 136 + kc * 32 + lk * 8];
        s8v Al = *(const s8v*)&t1l[rowA * 136 + kc * 32 + lk * 8];
        const int bo = kc * 5120 + lr * 40 + lk * 8;
        mfma8(Ws + SEG_F2_H + bo, Ws + SEG_F2_L + bo, Ah, Al, acc);
    }
    __syncthreads();   // all t1 reads done before tf overwrite
#pragma unroll
    for (int t = 0; t < 8; ++t)
#pragma unroll
        for (int r = 0; r < 4; ++r)
            tf[(16 * w + lk * 4 + r) * LDA + t * 16 + lr] = acc[t][r];
    __syncthreads();

    // ---- epilogue: cutoff, gather h[ind_j], write fp16 msg row at CSR slot pos[e]
#pragma unroll
    for (int i = 0; i < 4; ++i) {
        int e = e0 + rt * 4 + i;
        float rr = r_ij[e];
        float C = (rr < 5.0f) ? (0.5f * __cosf(rr * PI_OVER_CUT) + 0.5f) : 0.0f;
        int nj = ind_j[e];
        const float* hp = &h[(size_t)nj * DIM + ct * 8];
        float4 h0 = *(const float4*)hp, h1 = *(const float4*)(hp + 4);
        const float* ep = &tf[(rt * 4 + i) * LDA + ct * 8];
        float4 a0 = *(const float4*)ep, a1 = *(const float4*)(ep + 4);
        __half2 o0 = __floats2half2_rn(h0.x * a0.x * C, h0.y * a0.y * C);
        __half2 o1 = __floats2half2_rn(h0.z * a0.z * C, h0.w * a0.w * C);
        __half2 o2 = __floats2half2_rn(h1.x * a1.x * C, h1.y * a1.y * C);
        __half2 o3 = __floats2half2_rn(h1.z * a1.z * C, h1.w * a1.w * C);
        __half* mp = &msg[(size_t)pos[e] * DIM + ct * 8];   // byte off pos*256+ct*16: 16B-aligned
        *(uint4*)mp = make_uint4(*(unsigned int*)&o0, *(unsigned int*)&o1,
                                 *(unsigned int*)&o2, *(unsigned int*)&o3);
    }
}

// ---------------- Gather: agg[n] = sum of contiguous fp16 CSR msg rows ----------------
__global__ __launch_bounds__(BLK) void gather_kernel(const __half* __restrict__ msg,
                                                     const int* __restrict__ start,
                                                     const int* __restrict__ cnt,
                                                     float* __restrict__ agg) {
    const int wave = threadIdx.x >> 6;
    const int lane = threadIdx.x & 63;
    const int node = blockIdx.x * 4 + wave;
    if (node >= N_NODES_C) return;
    const int s = start[node];
    const int d = cnt[node];
    const __half* base = msg + (size_t)s * DIM + lane * 2;
    float ax = 0.f, ay = 0.f;
    int k = 0;
    for (; k + 1 < d; k += 2) {
        float2 fa = __half22float2(*(const __half2*)(base + (size_t)k * DIM));
        float2 fb = __half22float2(*(const __half2*)(base + (size_t)(k + 1) * DIM));
        ax += fa.x + fb.x;
        ay += fa.y + fb.y;
    }
    if (k < d) {
        float2 fa = __half22float2(*(const __half2*)(base + (size_t)k * DIM));
        ax += fa.x;
        ay += fa.y;
    }
    *(float2*)&agg[(size_t)node * DIM + lane * 2] = make_float2(ax, ay);
}

// ---------------- out = ssp(agg@W_out + b_out) @ W_lin + b_lin  (MFMA) ----------------
__global__ __launch_bounds__(BLK, 4) void node_out_mfma(const float* __restrict__ agg,
                                                        const unsigned short* __restrict__ Ws,
                                                        const float* __restrict__ b_out,
                                                        const float* __restrict__ b_lin,
                                                        float* __restrict__ out) {
    __shared__ __align__(16) char smem[34816];
    unsigned short* t1h = (unsigned short*)smem;
    unsigned short* t1l = t1h + 64 * 136;

    const int tid = threadIdx.x;
    const int w = tid >> 6, l = tid & 63, lr = l & 15, lk = l >> 4;
    const int n0 = blockIdx.x * TROWS;
    const int rowA = 16 * w + lr;
    const float* ar = agg + (size_t)(n0 + rowA) * DIM;

    f4v acc[8];
#pragma unroll
    for (int t = 0; t < 8; ++t) { float bv = b_out[t * 16 + lr]; acc[t] = (f4v){bv, bv, bv, bv}; }
#pragma unroll
    for (int kc = 0; kc < 4; ++kc) {
        const float* ap = ar + kc * 32 + lk * 8;
        float4 a0 = *(const float4*)ap, a1 = *(const float4*)(ap + 4);
        float av[8] = {a0.x, a0.y, a0.z, a0.w, a1.x, a1.y, a1.z, a1.w};
        s8v Ah, Al; split8t(av, Ah, Al);
        const int bo = kc * 5120 + lr * 40 + lk * 8;
        mfma8(Ws + SEG_OUT_H + bo, Ws + SEG_OUT_L + bo, Ah, Al, acc);
    }
#pragma unroll
    for (int t = 0; t < 8; ++t)
#pragma unroll
        for (int r = 0; r < 4; ++r) {
            float v = ssp_f(acc[t][r]);
            unsigned int u = __float_as_uint(v);
            float hf = __uint_as_float(u & 0xffff0000u);
            int idx = (16 * w + lk * 4 + r) * 136 + t * 16 + lr;
            t1h[idx] = (unsigned short)(u >> 16);
            t1l[idx] = (unsigned short)(__float_as_uint(v - hf) >> 16);
        }
    __syncthreads();

#pragma unroll
    for (int t = 0; t < 8; ++t) { float bv = b_lin[t * 16 + lr]; acc[t] = (f4v){bv, bv, bv, bv}; }
#pragma unroll
    for (int kc = 0; kc < 4; ++kc) {
        s8v Ah = *(const s8v*)&t1h[rowA * 136 + kc * 32 + lk * 8];
        s8v Al = *(const s8v*)&t1l[rowA * 136 + kc * 32 + lk * 8];
        const int bo = kc * 5120 + lr * 40 + lk * 8;
        mfma8(Ws + SEG_LIN_H + bo, Ws + SEG_LIN_L + bo, Ah, Al, acc);
    }
#pragma unroll
    for (int t = 0; t < 8; ++t)
#pragma unroll
        for (int r = 0; r < 4; ++r)
            out[(size_t)(n0 + 16 * w + lk * 4 + r) * DIM + t * 16 + lr] = acc[t][r];
}

// ================= vector fallback path (only if workspace too small) =================
__device__ __forceinline__ void stage_chunk(const float* __restrict__ B, int k0, int rows,
                                            float* __restrict__ Bc, int tid) {
    const int n4 = rows * (DIM / 4);
    const float4* Bg = (const float4*)B + (size_t)k0 * (DIM / 4);
    float4* Bc4 = (float4*)Bc;
    for (int i = tid; i < n4; i += BLK) Bc4[i] = Bg[i];
}

__device__ __forceinline__ void init_acc_bias(float acc[4][8], const float* __restrict__ b, int ct) {
    float4 bb0 = *(const float4*)&b[ct * 8];
    float4 bb1 = *(const float4*)&b[ct * 8 + 4];
#pragma unroll
    for (int i = 0; i < 4; ++i) {
        acc[i][0] = bb0.x; acc[i][1] = bb0.y; acc[i][2] = bb0.z; acc[i][3] = bb0.w;
        acc[i][4] = bb1.x; acc[i][5] = bb1.y; acc[i][6] = bb1.z; acc[i][7] = bb1.w;
    }
}

template <int KPAD>
__device__ __forceinline__ void gemm_tile(const float* __restrict__ A_lds, int lda,
                                          const float* __restrict__ Bglob,
                                          float* __restrict__ Bc,
                                          float acc[4][8], int rt, int ct, int tid) {
    for (int k0 = 0; k0 < KPAD; k0 += 32) {
        __syncthreads();
        stage_chunk(Bglob, k0, 32, Bc, tid);
        __syncthreads();
#pragma unroll 2
        for (int k4 = 0; k4 < 8; ++k4) {
            float4 av[4];
#pragma unroll
            for (int i = 0; i < 4; ++i)
                av[i] = *(const float4*)&A_lds[(rt * 4 + i) * lda + k0 + k4 * 4];
#pragma unroll
            for (int kk = 0; kk < 4; ++kk) {
                const float* bp = &Bc[(k4 * 4 + kk) * DIM + ct * 8];
                float4 b0 = *(const float4*)bp;
                float4 b1 = *(const float4*)(bp + 4);
#pragma unroll
                for (int i = 0; i < 4; ++i) {
                    float a = ((const float*)&av[i])[kk];
                    acc[i][0] = fmaf(a, b0.x, acc[i][0]);
                    acc[i][1] = fmaf(a, b0.y, acc[i][1]);
                    acc[i][2] = fmaf(a, b0.z, acc[i][2]);
                    acc[i][3] = fmaf(a, b0.w, acc[i][3]);
                    acc[i][4] = fmaf(a, b1.x, acc[i][4]);
                    acc[i][5] = fmaf(a, b1.y, acc[i][5]);
                    acc[i][6] = fmaf(a, b1.z, acc[i][6]);
                    acc[i][7] = fmaf(a, b1.w, acc[i][7]);
                }
            }
        }
    }
}

template <int NK2>
__device__ __forceinline__ void gemm1_direct(const float* const (&frow)[4], int k2base,
                                             const float* __restrict__ Bc,
                                             float acc[4][8], int ct) {
#pragma unroll 4
    for (int k2 = 0; k2 < NK2; ++k2) {
        float2 a2[4];
#pragma unroll
        for (int i = 0; i < 4; ++i)
            a2[i] = *(const float2*)(frow[i] + (k2base + k2) * 2);
#pragma unroll
        for (int kk = 0; kk < 2; ++kk) {
            const float* bp = &Bc[(k2 * 2 + kk) * DIM + ct * 8];
            float4 b0 = *(const float4*)bp;
            float4 b1 = *(const float4*)(bp + 4);
#pragma unroll
            for (int i = 0; i < 4; ++i) {
                float a = kk ? a2[i].y : a2[i].x;
                acc[i][0] = fmaf(a, b0.x, acc[i][0]);
                acc[i][1] = fmaf(a, b0.y, acc[i][1]);
                acc[i][2] = fmaf(a, b0.z, acc[i][2]);
                acc[i][3] = fmaf(a, b0.w, acc[i][3]);
                acc[i][4] = fmaf(a, b1.x, acc[i][4]);
                acc[i][5] = fmaf(a, b1.y, acc[i][5]);
                acc[i][6] = fmaf(a, b1.z, acc[i][6]);
                acc[i][7] = fmaf(a, b1.w, acc[i][7]);
            }
        }
    }
}

__global__ __launch_bounds__(BLK) void node_in2f_fb(const float* __restrict__ x,
                                                    const float* __restrict__ W,
                                                    float* __restrict__ h) {
    __shared__ float At[TROWS * LDA];
    __shared__ float Bc[32 * DIM];
    const int tid = threadIdx.x;
    const int rt = tid >> 4, ct = tid & 15;
    const int n0 = blockIdx.x * TROWS;
    for (int i = tid; i < TROWS * (DIM / 4); i += BLK) {
        int row = i >> 5, c4 = i & 31;
        *(float4*)&At[row * LDA + c4 * 4] = *(const float4*)&x[(size_t)(n0 + row) * DIM + c4 * 4];
    }
    float acc[4][8];
#pragma unroll
    for (int i = 0; i < 4; ++i)
#pragma unroll
        for (int j = 0; j < 8; ++j) acc[i][j] = 0.f;
    gemm_tile<DIM>(At, LDA, W, Bc, acc, rt, ct, tid);
#pragma unroll
    for (int i = 0; i < 4; ++i) {
        float* hp = &h[(size_t)(n0 + rt * 4 + i) * DIM + ct * 8];
        *(float4*)hp = make_float4(acc[i][0], acc[i][1], acc[i][2], acc[i][3]);
        *(float4*)(hp + 4) = make_float4(acc[i][4], acc[i][5], acc[i][6], acc[i][7]);
    }
}

__global__ __launch_bounds__(BLK) void node_out_fb(const float* __restrict__ agg,
                                                   const float* __restrict__ W_out,
                                                   const float* __restrict__ b_out,
                                                   const float* __restrict__ W_lin,
                                                   const float* __restrict__ b_lin,
                                                   float* __restrict__ out) {
    __shared__ float At[TROWS * LDA];
    __shared__ float Bc[32 * DIM];
    const int tid = threadIdx.x;
    const int rt = tid >> 4, ct = tid & 15;
    const int n0 = blockIdx.x * TROWS;
    for (int i = tid; i < TROWS * (DIM / 4); i += BLK) {
        int row = i >> 5, c4 = i & 31;
        *(float4*)&At[row * LDA + c4 * 4] = *(const float4*)&agg[(size_t)(n0 + row) * DIM + c4 * 4];
    }
    float acc[4][8];
    init_acc_bias(acc, b_out, ct);
    gemm_tile<DIM>(At, LDA, W_out, Bc, acc, rt, ct, tid);
    __syncthreads();
#pragma unroll
    for (int i = 0; i < 4; ++i) {
        float* tp = &At[(rt * 4 + i) * LDA + ct * 8];
        *(float4*)tp = make_float4(ssp_f(acc[i][0]), ssp_f(acc[i][1]),
                                   ssp_f(acc[i][2]), ssp_f(acc[i][3]));
        *(float4*)(tp + 4) = make_float4(ssp_f(acc[i][4]), ssp_f(acc[i][5]),
                                         ssp_f(acc[i][6]), ssp_f(acc[i][7]));
    }
    init_acc_bias(acc, b_lin, ct);
    gemm_tile<DIM>(At, LDA, W_lin, Bc, acc, rt, ct, tid);
#pragma unroll
    for (int i = 0; i < 4; ++i) {
        float* op = &out[(size_t)(n0 + rt * 4 + i) * DIM + ct * 8];
        *(float4*)op = make_float4(acc[i][0], acc[i][1], acc[i][2], acc[i][3]);
        *(float4*)(op + 4) = make_float4(acc[i][4], acc[i][5], acc[i][6], acc[i][7]);
    }
}

__global__ __launch_bounds__(BLK) void edge_kernel_atomic(const float* __restrict__ f_ij,
                                                          const float* __restrict__ r_ij,
                                                          const int* __restrict__ ind_i,
                                                          const int* __restrict__ ind_j,
                                                          const float* __restrict__ W_f1,
                                                          const float* __restrict__ b_f1,
                                                          const float* __restrict__ W_f2,
                                                          const float* __restrict__ b_f2,
                                                          const float* __restrict__ h,
                                                          float* __restrict__ agg) {
    __shared__ float t1[TROWS * LDA];
    __shared__ float Bc[32 * DIM];
    const int tid = threadIdx.x;
    const int rt = tid >> 4, ct = tid & 15;
    const int e0 = blockIdx.x * TROWS;
    const float* frow[4];
#pragma unroll
    for (int i = 0; i < 4; ++i) frow[i] = f_ij + (size_t)(e0 + rt * 4 + i) * NB;
    float acc[4][8];
    init_acc_bias(acc, b_f1, ct);
    stage_chunk(W_f1, 0, 32, Bc, tid);
    __syncthreads();
    gemm1_direct<16>(frow, 0, Bc, acc, ct);
    __syncthreads();
    stage_chunk(W_f1, 32, 18, Bc, tid);
    __syncthreads();
    gemm1_direct<9>(frow, 16, Bc, acc, ct);
#pragma unroll
    for (int i = 0; i < 4; ++i) {
        float* tp = &t1[(rt * 4 + i) * LDA + ct * 8];
        *(float4*)tp = make_float4(ssp_f(acc[i][0]), ssp_f(acc[i][1]),
                                   ssp_f(acc[i][2]), ssp_f(acc[i][3]));
        *(float4*)(tp + 4) = make_float4(ssp_f(acc[i][4]), ssp_f(acc[i][5]),
                                         ssp_f(acc[i][6]), ssp_f(acc[i][7]));
    }
    init_acc_bias(acc, b_f2, ct);
    gemm_tile<DIM>(t1, LDA, W_f2, Bc, acc, rt, ct, tid);
#pragma unroll
    for (int i = 0; i < 4; ++i) {
        int e = e0 + rt * 4 + i;
        float r = r_ij[e];
        float C = (r < 5.0f) ? 0.5f * (cosf(r * PI_OVER_CUT) + 1.0f) : 0.0f;
        int nj = ind_j[e];
        int ni = ind_i[e];
        const float* hp = &h[(size_t)nj * DIM + ct * 8];
        float4 h0 = *(const float4*)hp;
        float4 h1 = *(const float4*)(hp + 4);
        float* ap = &agg[(size_t)ni * DIM + ct * 8];
        atomicAdd(ap + 0, h0.x * acc[i][0] * C);
        atomicAdd(ap + 1, h0.y * acc[i][1] * C);
        atomicAdd(ap + 2, h0.z * acc[i][2] * C);
        atomicAdd(ap + 3, h0.w * acc[i][3] * C);
        atomicAdd(ap + 4, h1.x * acc[i][4] * C);
        atomicAdd(ap + 5, h1.y * acc[i][5] * C);
        atomicAdd(ap + 6, h1.z * acc[i][6] * C);
        atomicAdd(ap + 7, h1.w * acc[i][7] * C);
    }
}

extern "C" void kernel_launch(void* const* d_in, const int* in_sizes, int n_in,
                              void* d_out, int out_size, void* d_ws, size_t ws_size,
                              hipStream_t stream) {
    const float* x      = (const float*)d_in[0];
    const float* r_ij   = (const float*)d_in[1];
    const float* f_ij   = (const float*)d_in[2];
    const int*   ind_i  = (const int*)d_in[3];
    const int*   ind_j  = (const int*)d_in[4];
    const float* W_in2f = (const float*)d_in[5];
    const float* W_f1   = (const float*)d_in[6];
    const float* b_f1   = (const float*)d_in[7];
    const float* W_f2   = (const float*)d_in[8];
    const float* b_f2   = (const float*)d_in[9];
    const float* W_out  = (const float*)d_in[10];
    const float* b_out  = (const float*)d_in[11];
    const float* W_lin  = (const float*)d_in[12];
    const float* b_lin  = (const float*)d_in[13];
    float* out = (float*)d_out;

    char* ws = (char*)d_ws;
    size_t off = 0;
    auto alloc = [&](size_t bytes) {
        char* p = ws + off;
        off = (off + bytes + 511) & ~(size_t)511;
        return p;
    };
    unsigned short* Wsplit = (unsigned short*)alloc(WSPLIT_USHORTS * sizeof(unsigned short));
    float*  h      = (float*)alloc((size_t)N_NODES_C * DIM * sizeof(float));
    float*  agg    = (float*)alloc((size_t)N_NODES_C * DIM * sizeof(float));
    __half* msg    = (__half*)alloc((size_t)N_EDGES_C * DIM * sizeof(__half));
    int*    pos    = (int*)alloc((size_t)N_EDGES_C * sizeof(int));
    int*    cnt    = (int*)alloc((size_t)N_NODES_C * sizeof(int));
    int*    startA = (int*)alloc((size_t)N_NODES_C * sizeof(int));
    int*    cursor = (int*)alloc((size_t)N_NODES_C * sizeof(int));
    int*    bsum   = (int*)alloc((size_t)NSCAN_BLK * sizeof(int));
    const bool have_ws = (off <= ws_size);

    if (have_ws) {
        split5_kernel<<<(18 * 4096 + BLK - 1) / BLK, BLK, 0, stream>>>(
            W_in2f, W_f1, W_f2, W_out, W_lin, Wsplit);

        node_in2f_mfma<<<N_NODES_C / TROWS, BLK, 0, stream>>>(x, Wsplit, h);

        hipMemsetAsync(cnt, 0, (size_t)N_NODES_C * sizeof(int), stream);
        hist_kernel<<<(N_EDGES_C + BLK - 1) / BLK, BLK, 0, stream>>>(ind_i, cnt);
        scan1_kernel<<<NSCAN_BLK, BLK, 0, stream>>>(cnt, startA, bsum);
        scan2_kernel<<<1, BLK, 0, stream>>>(bsum);
        scan3_kernel<<<NSCAN_BLK, BLK, 0, stream>>>(startA, cursor, bsum);
        place_kernel<<<(N_EDGES_C + BLK - 1) / BLK, BLK, 0, stream>>>(ind_i, cursor, pos);

        edge_kernel_mfma<<<N_EDGES_C / TROWS, BLK, 0, stream>>>(
            f_ij, r_ij, ind_j, pos, Wsplit, b_f1, b_f2, h, msg);
        gather_kernel<<<(N_NODES_C + 3) / 4, BLK, 0, stream>>>(msg, startA, cnt, agg);

        node_out_mfma<<<N_NODES_C / TROWS, BLK, 0, stream>>>(agg, Wsplit, b_out, b_lin, out);
    } else {
        // minimal-workspace vector fallback (h + agg only)
        float* h2   = (float*)d_ws;
        float* agg2 = h2 + (size_t)N_NODES_C * DIM;
        node_in2f_fb<<<N_NODES_C / TROWS, BLK, 0, stream>>>(x, W_in2f, h2);
        hipMemsetAsync(agg2, 0, (size_t)N_NODES_C * DIM * sizeof(float), stream);
        edge_kernel_atomic<<<N_EDGES_C / TROWS, BLK, 0, stream>>>(
            f_ij, r_ij, ind_i, ind_j, W_f1, b_f1, W_f2, b_f2, h2, agg2);
        node_out_fb<<<N_NODES_C / TROWS, BLK, 0, stream>>>(agg2, W_out, b_out, W_lin, b_lin, out);
    }
}

// Round 12
// 308.398 us; speedup vs baseline: 1.4335x; 1.1627x over previous
//
#include <hip/hip_runtime.h>
#include <hip/hip_fp16.h>

#define N_NODES_C 40000
#define N_EDGES_C 640000
#define DIM 128
#define NB 50
#define LDA 132       // f32 transpose-buffer leading dim (528B rows: 16B-aligned)
#define BLK 256
#define TROWS 64
#define LOG2_C 0.6931471805599453f
#define PI_OVER_CUT 0.6283185307179586f  // pi/5
#define NSCAN_BLK 157  // ceil(40000/256)

typedef __attribute__((ext_vector_type(8))) short s8v;   // 8 bf16 = A/B frag of 16x16x32
typedef __attribute__((ext_vector_type(4))) float f4v;   // C/D frag

#define MFMA_BF16 __builtin_amdgcn_mfma_f32_16x16x32_bf16

// Wsplit segment offsets (ushort units). Layout per weight: [nc][128 col][40], k at col*40+k.
#define SEG_IN2F_H 0
#define SEG_IN2F_L 20480
#define SEG_F1_H   40960
#define SEG_F1_L   51200
#define SEG_F2_H   61440
#define SEG_F2_L   81920
#define SEG_OUT_H  102400
#define SEG_OUT_L  122880
#define SEG_LIN_H  143360
#define SEG_LIN_L  163840
#define WSPLIT_USHORTS 184320

__device__ __forceinline__ unsigned short f2bf(float x) {   // RNE (pre-split kernel only)
    unsigned int u = __float_as_uint(x);
    u += 0x7fffu + ((u >> 16) & 1u);
    return (unsigned short)(u >> 16);
}
__device__ __forceinline__ float bf2f(unsigned short h) {
    return __uint_as_float(((unsigned int)h) << 16);
}
__device__ __forceinline__ float ssp_f(float t) {
    float e = __expf(-fabsf(t));
    return fmaxf(t, 0.0f) + __logf(1.0f + e) - LOG2_C;
}
// truncation split of 8 f32 -> bf16 hi/lo frags (residual exact)
__device__ __forceinline__ void split8t(const float* av, s8v& Ah, s8v& Al) {
#pragma unroll
    for (int j = 0; j < 8; j += 2) {
        unsigned int u0 = __float_as_uint(av[j]);
        unsigned int u1 = __float_as_uint(av[j + 1]);
        float h0 = __uint_as_float(u0 & 0xffff0000u);
        float h1 = __uint_as_float(u1 & 0xffff0000u);
        unsigned int r0 = __float_as_uint(av[j] - h0);
        unsigned int r1 = __float_as_uint(av[j + 1] - h1);
        ((unsigned int*)&Ah)[j >> 1] = __builtin_amdgcn_perm(u1, u0, 0x07060302);
        ((unsigned int*)&Al)[j >> 1] = __builtin_amdgcn_perm(r1, r0, 0x07060302);
    }
}
// 4 col-tiles x 2 row-tiles x 3-term split MFMA; B batch shared by both row-tiles.
// Per kc: 8 B-loads (halved vs full-width), 24 MFMAs.
__device__ __forceinline__ void mfma4x2(const unsigned short* __restrict__ bh,
                                        const unsigned short* __restrict__ bl,
                                        const s8v& Ah0, const s8v& Al0,
                                        const s8v& Ah1, const s8v& Al1,
                                        f4v acc0[4], f4v acc1[4]) {
    s8v B[4];
#pragma unroll
    for (int t = 0; t < 4; ++t) B[t] = *(const s8v*)(bl + t * 640);
#pragma unroll
    for (int t = 0; t < 4; ++t) {
        acc0[t] = MFMA_BF16(Ah0, B[t], acc0[t], 0, 0, 0);
        acc1[t] = MFMA_BF16(Ah1, B[t], acc1[t], 0, 0, 0);
    }
#pragma unroll
    for (int t = 0; t < 4; ++t) B[t] = *(const s8v*)(bh + t * 640);
#pragma unroll
    for (int t = 0; t < 4; ++t) {
        acc0[t] = MFMA_BF16(Al0, B[t], acc0[t], 0, 0, 0);
        acc0[t] = MFMA_BF16(Ah0, B[t], acc0[t], 0, 0, 0);
        acc1[t] = MFMA_BF16(Al1, B[t], acc1[t], 0, 0, 0);
        acc1[t] = MFMA_BF16(Ah1, B[t], acc1[t], 0, 0, 0);
    }
}

// ---------------- weight pre-split (once per launch) ----------------
__global__ __launch_bounds__(BLK) void split5_kernel(const float* __restrict__ Wa,
                                                     const float* __restrict__ Wb,
                                                     const float* __restrict__ Wc,
                                                     const float* __restrict__ Wd,
                                                     const float* __restrict__ We,
                                                     unsigned short* __restrict__ Ws) {
    int i = blockIdx.x * BLK + threadIdx.x;
    if (i >= 18 * 4096) return;
    int chunk = i >> 12, r = i & 4095, k = r & 31, col = r >> 5;
    const float* W; int Kr, ck, hb, lb;
    if (chunk < 4)       { W = Wa; Kr = 128; ck = chunk;      hb = SEG_IN2F_H; lb = SEG_IN2F_L; }
    else if (chunk < 6)  { W = Wb; Kr = 50;  ck = chunk - 4;  hb = SEG_F1_H;   lb = SEG_F1_L; }
    else if (chunk < 10) { W = Wc; Kr = 128; ck = chunk - 6;  hb = SEG_F2_H;   lb = SEG_F2_L; }
    else if (chunk < 14) { W = Wd; Kr = 128; ck = chunk - 10; hb = SEG_OUT_H;  lb = SEG_OUT_L; }
    else                 { W = We; Kr = 128; ck = chunk - 14; hb = SEG_LIN_H;  lb = SEG_LIN_L; }
    int krow = ck * 32 + k;
    float v = (krow < Kr) ? W[(size_t)krow * DIM + col] : 0.f;
    unsigned short h16 = f2bf(v);
    int o = ck * 5120 + col * 40 + k;
    Ws[hb + o] = h16;
    Ws[lb + o] = f2bf(v - bf2f(h16));
}

// ---------------- h = x @ W_in2f  (MFMA, no LDS, row-pair x col-half split) ----------------
__global__ __launch_bounds__(BLK, 4) void node_in2f_mfma(const float* __restrict__ x,
                                                         const unsigned short* __restrict__ Ws,
                                                         float* __restrict__ h) {
    const int tid = threadIdx.x;
    const int w = tid >> 6, l = tid & 63, lr = l & 15, lk = l >> 4;
    const int rpair = w & 1, colbase = (w >> 1) * 64;
    const int n0 = blockIdx.x * TROWS;
    const int rowA0 = rpair * 32 + lr, rowA1 = rowA0 + 16;
    const float* xr0 = x + (size_t)(n0 + rowA0) * DIM;
    const float* xr1 = x + (size_t)(n0 + rowA1) * DIM;

    f4v acc0[4], acc1[4];
#pragma unroll
    for (int t = 0; t < 4; ++t) {
        acc0[t] = (f4v){0.f, 0.f, 0.f, 0.f};
        acc1[t] = (f4v){0.f, 0.f, 0.f, 0.f};
    }
#pragma unroll
    for (int kc = 0; kc < 4; ++kc) {
        const float* ap0 = xr0 + kc * 32 + lk * 8;
        const float* ap1 = xr1 + kc * 32 + lk * 8;
        float4 a0 = *(const float4*)ap0, a1 = *(const float4*)(ap0 + 4);
        float4 b0 = *(const float4*)ap1, b1 = *(const float4*)(ap1 + 4);
        float av0[8] = {a0.x, a0.y, a0.z, a0.w, a1.x, a1.y, a1.z, a1.w};
        float av1[8] = {b0.x, b0.y, b0.z, b0.w, b1.x, b1.y, b1.z, b1.w};
        s8v Ah0, Al0, Ah1, Al1;
        split8t(av0, Ah0, Al0);
        split8t(av1, Ah1, Al1);
        const int bo = kc * 5120 + (colbase + lr) * 40 + lk * 8;
        mfma4x2(Ws + SEG_IN2F_H + bo, Ws + SEG_IN2F_L + bo, Ah0, Al0, Ah1, Al1, acc0, acc1);
    }
#pragma unroll
    for (int t = 0; t < 4; ++t)
#pragma unroll
        for (int r = 0; r < 4; ++r) {
            int col = colbase + t * 16 + lr;
            h[(size_t)(n0 + rpair * 32 + lk * 4 + r) * DIM + col] = acc0[t][r];
            h[(size_t)(n0 + rpair * 32 + 16 + lk * 4 + r) * DIM + col] = acc1[t][r];
        }
}

// ---------------- CSR build ----------------
__global__ __launch_bounds__(BLK) void hist_kernel(const int* __restrict__ ind_i,
                                                   int* __restrict__ cnt) {
    int e = blockIdx.x * BLK + threadIdx.x;
    if (e < N_EDGES_C) atomicAdd(&cnt[ind_i[e]], 1);
}

__global__ __launch_bounds__(BLK) void scan1_kernel(const int* __restrict__ cnt,
                                                    int* __restrict__ excl,
                                                    int* __restrict__ bsum) {
    __shared__ int s[BLK];
    const int tid = threadIdx.x;
    const int idx = blockIdx.x * BLK + tid;
    int v = (idx < N_NODES_C) ? cnt[idx] : 0;
    s[tid] = v;
    __syncthreads();
    for (int off = 1; off < BLK; off <<= 1) {
        int t = (tid >= off) ? s[tid - off] : 0;
        __syncthreads();
        s[tid] += t;
        __syncthreads();
    }
    if (idx < N_NODES_C) excl[idx] = s[tid] - v;
    if (tid == BLK - 1) bsum[blockIdx.x] = s[tid];
}

__global__ __launch_bounds__(BLK) void scan2_kernel(int* __restrict__ bsum) {
    __shared__ int s[BLK];
    const int tid = threadIdx.x;
    int v = (tid < NSCAN_BLK) ? bsum[tid] : 0;
    s[tid] = v;
    __syncthreads();
    for (int off = 1; off < BLK; off <<= 1) {
        int t = (tid >= off) ? s[tid - off] : 0;
        __syncthreads();
        s[tid] += t;
        __syncthreads();
    }
    if (tid < NSCAN_BLK) bsum[tid] = s[tid] - v;  // exclusive
}

__global__ __launch_bounds__(BLK) void scan3_kernel(int* __restrict__ start,
                                                    int* __restrict__ cursor,
                                                    const int* __restrict__ bsum) {
    const int idx = blockIdx.x * BLK + threadIdx.x;
    if (idx < N_NODES_C) {
        int v = start[idx] + bsum[blockIdx.x];
        start[idx] = v;
        cursor[idx] = v;
    }
}

// place: writes pos[e] = CSR slot so the edge kernel writes msg in CSR order
__global__ __launch_bounds__(BLK) void place_kernel(const int* __restrict__ ind_i,
                                                    int* __restrict__ cursor,
                                                    int* __restrict__ pos) {
    int e = blockIdx.x * BLK + threadIdx.x;
    if (e < N_EDGES_C) {
        int slot = atomicAdd(&cursor[ind_i[e]], 1);
        pos[e] = slot;
    }
}

// ---------------- Edge kernel: full MFMA; row-pair x col-half wave split ----------------
// LDS (34816B): t1h[64][136] + t1l[64][136] ushort; alias tf f32[64][132] post-GEMM2.
__global__ __launch_bounds__(BLK, 4) void edge_kernel_mfma(const float* __restrict__ f_ij,
                                                           const float* __restrict__ r_ij,
                                                           const int* __restrict__ ind_j,
                                                           const int* __restrict__ pos,
                                                           const unsigned short* __restrict__ Ws,
                                                           const float* __restrict__ b_f1,
                                                           const float* __restrict__ b_f2,
                                                           const float* __restrict__ h,
                                                           __half* __restrict__ msg) {
    __shared__ __align__(16) char smem[34816];
    unsigned short* t1h = (unsigned short*)smem;          // [64][136]
    unsigned short* t1l = t1h + 64 * 136;
    float* tf = (float*)smem;                             // [64][132] alias (post-GEMM2)

    const int tid = threadIdx.x;
    const int w = tid >> 6, l = tid & 63, lr = l & 15, lk = l >> 4;
    const int rt = tid >> 4, ct = tid & 15;
    const int rpair = w & 1, colbase = (w >> 1) * 64;
    const int e0 = blockIdx.x * TROWS;  // 640000 % 64 == 0
    const int rowA0 = rpair * 32 + lr, rowA1 = rowA0 + 16;

    // ---- GEMM1: t_pre = f @ W1 + b1; A in-reg from global f_ij (float2, 8B-aligned)
    f4v acc0[4], acc1[4];
#pragma unroll
    for (int t = 0; t < 4; ++t) {
        float bv = b_f1[colbase + t * 16 + lr];
        acc0[t] = (f4v){bv, bv, bv, bv};
        acc1[t] = (f4v){bv, bv, bv, bv};
    }
    const float* fr0 = f_ij + (size_t)(e0 + rowA0) * NB;
    const float* fr1 = f_ij + (size_t)(e0 + rowA1) * NB;
#pragma unroll
    for (int kc = 0; kc < 2; ++kc) {
        int kb = kc * 32 + lk * 8;
        float av0[8], av1[8];
#pragma unroll
        for (int ii = 0; ii < 4; ++ii) {
            int k = kb + ii * 2;                      // pairs never straddle 50 (even)
            float2 v0 = (k < NB) ? *(const float2*)(fr0 + k) : make_float2(0.f, 0.f);
            float2 v1 = (k < NB) ? *(const float2*)(fr1 + k) : make_float2(0.f, 0.f);
            av0[ii * 2] = v0.x; av0[ii * 2 + 1] = v0.y;
            av1[ii * 2] = v1.x; av1[ii * 2 + 1] = v1.y;
        }
        s8v Ah0, Al0, Ah1, Al1;
        split8t(av0, Ah0, Al0);
        split8t(av1, Ah1, Al1);
        const int bo = kc * 5120 + (colbase + lr) * 40 + lk * 8;
        mfma4x2(Ws + SEG_F1_H + bo, Ws + SEG_F1_L + bo, Ah0, Al0, Ah1, Al1, acc0, acc1);
    }
    // C (row rpair*32[+16]+lk*4+r, col colbase+t*16+lr): ssp + split into t1h/t1l
#pragma unroll
    for (int t = 0; t < 4; ++t)
#pragma unroll
        for (int r = 0; r < 4; ++r) {
            int col = colbase + t * 16 + lr;
            {
                float v = ssp_f(acc0[t][r]);
                unsigned int u = __float_as_uint(v);
                float hf = __uint_as_float(u & 0xffff0000u);
                int idx = (rpair * 32 + lk * 4 + r) * 136 + col;
                t1h[idx] = (unsigned short)(u >> 16);
                t1l[idx] = (unsigned short)(__float_as_uint(v - hf) >> 16);
            }
            {
                float v = ssp_f(acc1[t][r]);
                unsigned int u = __float_as_uint(v);
                float hf = __uint_as_float(u & 0xffff0000u);
                int idx = (rpair * 32 + 16 + lk * 4 + r) * 136 + col;
                t1h[idx] = (unsigned short)(u >> 16);
                t1l[idx] = (unsigned short)(__float_as_uint(v - hf) >> 16);
            }
        }
    __syncthreads();

    // ---- GEMM2: msg_pre = t1 @ W2 + b2; A-frags pre-split from LDS (b128)
#pragma unroll
    for (int t = 0; t < 4; ++t) {
        float bv = b_f2[colbase + t * 16 + lr];
        acc0[t] = (f4v){bv, bv, bv, bv};
        acc1[t] = (f4v){bv, bv, bv, bv};
    }
#pragma unroll
    for (int kc = 0; kc < 4; ++kc) {
        s8v Ah0 = *(const s8v*)&t1h[rowA0 * 136 + kc * 32 + lk * 8];
        s8v Al0 = *(const s8v*)&t1l[rowA0 * 136 + kc * 32 + lk * 8];
        s8v Ah1 = *(const s8v*)&t1h[rowA1 * 136 + kc * 32 + lk * 8];
        s8v Al1 = *(const s8v*)&t1l[rowA1 * 136 + kc * 32 + lk * 8];
        const int bo = kc * 5120 + (colbase + lr) * 40 + lk * 8;
        mfma4x2(Ws + SEG_F2_H + bo, Ws + SEG_F2_L + bo, Ah0, Al0, Ah1, Al1, acc0, acc1);
    }
    __syncthreads();   // all t1 reads done before tf overwrite
#pragma unroll
    for (int t = 0; t < 4; ++t)
#pragma unroll
        for (int r = 0; r < 4; ++r) {
            int col = colbase + t * 16 + lr;
            tf[(rpair * 32 + lk * 4 + r) * LDA + col] = acc0[t][r];
            tf[(rpair * 32 + 16 + lk * 4 + r) * LDA + col] = acc1[t][r];
        }
    __syncthreads();

    // ---- epilogue: cutoff, gather h[ind_j], write fp16 msg row at CSR slot pos[e]
#pragma unroll
    for (int i = 0; i < 4; ++i) {
        int e = e0 + rt * 4 + i;
        float rr = r_ij[e];
        float C = (rr < 5.0f) ? (0.5f * __cosf(rr * PI_OVER_CUT) + 0.5f) : 0.0f;
        int nj = ind_j[e];
        const float* hp = &h[(size_t)nj * DIM + ct * 8];
        float4 h0 = *(const float4*)hp, h1 = *(const float4*)(hp + 4);
        const float* ep = &tf[(rt * 4 + i) * LDA + ct * 8];
        float4 a0 = *(const float4*)ep, a1 = *(const float4*)(ep + 4);
        __half2 o0 = __floats2half2_rn(h0.x * a0.x * C, h0.y * a0.y * C);
        __half2 o1 = __floats2half2_rn(h0.z * a0.z * C, h0.w * a0.w * C);
        __half2 o2 = __floats2half2_rn(h1.x * a1.x * C, h1.y * a1.y * C);
        __half2 o3 = __floats2half2_rn(h1.z * a1.z * C, h1.w * a1.w * C);
        __half* mp = &msg[(size_t)pos[e] * DIM + ct * 8];   // 16B-aligned
        *(uint4*)mp = make_uint4(*(unsigned int*)&o0, *(unsigned int*)&o1,
                                 *(unsigned int*)&o2, *(unsigned int*)&o3);
    }
}

// ---------------- Gather: agg[n] = sum of contiguous fp16 CSR msg rows ----------------
__global__ __launch_bounds__(BLK) void gather_kernel(const __half* __restrict__ msg,
                                                     const int* __restrict__ start,
                                                     const int* __restrict__ cnt,
                                                     float* __restrict__ agg) {
    const int wave = threadIdx.x >> 6;
    const int lane = threadIdx.x & 63;
    const int node = blockIdx.x * 4 + wave;
    if (node >= N_NODES_C) return;
    const int s = start[node];
    const int d = cnt[node];
    const __half* base = msg + (size_t)s * DIM + lane * 2;
    float ax = 0.f, ay = 0.f;
    int k = 0;
    for (; k + 1 < d; k += 2) {
        float2 fa = __half22float2(*(const __half2*)(base + (size_t)k * DIM));
        float2 fb = __half22float2(*(const __half2*)(base + (size_t)(k + 1) * DIM));
        ax += fa.x + fb.x;
        ay += fa.y + fb.y;
    }
    if (k < d) {
        float2 fa = __half22float2(*(const __half2*)(base + (size_t)k * DIM));
        ax += fa.x;
        ay += fa.y;
    }
    *(float2*)&agg[(size_t)node * DIM + lane * 2] = make_float2(ax, ay);
}

// ---------------- out = ssp(agg@W_out + b_out) @ W_lin + b_lin  (MFMA, split waves) ------
__global__ __launch_bounds__(BLK, 4) void node_out_mfma(const float* __restrict__ agg,
                                                        const unsigned short* __restrict__ Ws,
                                                        const float* __restrict__ b_out,
                                                        const float* __restrict__ b_lin,
                                                        float* __restrict__ out) {
    __shared__ __align__(16) char smem[34816];
    unsigned short* t1h = (unsigned short*)smem;
    unsigned short* t1l = t1h + 64 * 136;

    const int tid = threadIdx.x;
    const int w = tid >> 6, l = tid & 63, lr = l & 15, lk = l >> 4;
    const int rpair = w & 1, colbase = (w >> 1) * 64;
    const int n0 = blockIdx.x * TROWS;
    const int rowA0 = rpair * 32 + lr, rowA1 = rowA0 + 16;
    const float* ar0 = agg + (size_t)(n0 + rowA0) * DIM;
    const float* ar1 = agg + (size_t)(n0 + rowA1) * DIM;

    f4v acc0[4], acc1[4];
#pragma unroll
    for (int t = 0; t < 4; ++t) {
        float bv = b_out[colbase + t * 16 + lr];
        acc0[t] = (f4v){bv, bv, bv, bv};
        acc1[t] = (f4v){bv, bv, bv, bv};
    }
#pragma unroll
    for (int kc = 0; kc < 4; ++kc) {
        const float* ap0 = ar0 + kc * 32 + lk * 8;
        const float* ap1 = ar1 + kc * 32 + lk * 8;
        float4 a0 = *(const float4*)ap0, a1 = *(const float4*)(ap0 + 4);
        float4 b0 = *(const float4*)ap1, b1 = *(const float4*)(ap1 + 4);
        float av0[8] = {a0.x, a0.y, a0.z, a0.w, a1.x, a1.y, a1.z, a1.w};
        float av1[8] = {b0.x, b0.y, b0.z, b0.w, b1.x, b1.y, b1.z, b1.w};
        s8v Ah0, Al0, Ah1, Al1;
        split8t(av0, Ah0, Al0);
        split8t(av1, Ah1, Al1);
        const int bo = kc * 5120 + (colbase + lr) * 40 + lk * 8;
        mfma4x2(Ws + SEG_OUT_H + bo, Ws + SEG_OUT_L + bo, Ah0, Al0, Ah1, Al1, acc0, acc1);
    }
    // v = ssp(C) split into LDS
#pragma unroll
    for (int t = 0; t < 4; ++t)
#pragma unroll
        for (int r = 0; r < 4; ++r) {
            int col = colbase + t * 16 + lr;
            {
                float v = ssp_f(acc0[t][r]);
                unsigned int u = __float_as_uint(v);
                float hf = __uint_as_float(u & 0xffff0000u);
                int idx = (rpair * 32 + lk * 4 + r) * 136 + col;
                t1h[idx] = (unsigned short)(u >> 16);
                t1l[idx] = (unsigned short)(__float_as_uint(v - hf) >> 16);
            }
            {
                float v = ssp_f(acc1[t][r]);
                unsigned int u = __float_as_uint(v);
                float hf = __uint_as_float(u & 0xffff0000u);
                int idx = (rpair * 32 + 16 + lk * 4 + r) * 136 + col;
                t1h[idx] = (unsigned short)(u >> 16);
                t1l[idx] = (unsigned short)(__float_as_uint(v - hf) >> 16);
            }
        }
    __syncthreads();

#pragma unroll
    for (int t = 0; t < 4; ++t) {
        float bv = b_lin[colbase + t * 16 + lr];
        acc0[t] = (f4v){bv, bv, bv, bv};
        acc1[t] = (f4v){bv, bv, bv, bv};
    }
#pragma unroll
    for (int kc = 0; kc < 4; ++kc) {
        s8v Ah0 = *(const s8v*)&t1h[rowA0 * 136 + kc * 32 + lk * 8];
        s8v Al0 = *(const s8v*)&t1l[rowA0 * 136 + kc * 32 + lk * 8];
        s8v Ah1 = *(const s8v*)&t1h[rowA1 * 136 + kc * 32 + lk * 8];
        s8v Al1 = *(const s8v*)&t1l[rowA1 * 136 + kc * 32 + lk * 8];
        const int bo = kc * 5120 + (colbase + lr) * 40 + lk * 8;
        mfma4x2(Ws + SEG_LIN_H + bo, Ws + SEG_LIN_L + bo, Ah0, Al0, Ah1, Al1, acc0, acc1);
    }
#pragma unroll
    for (int t = 0; t < 4; ++t)
#pragma unroll
        for (int r = 0; r < 4; ++r) {
            int col = colbase + t * 16 + lr;
            out[(size_t)(n0 + rpair * 32 + lk * 4 + r) * DIM + col] = acc0[t][r];
            out[(size_t)(n0 + rpair * 32 + 16 + lk * 4 + r) * DIM + col] = acc1[t][r];
        }
}

// ================= vector fallback path (only if workspace too small) =================
__device__ __forceinline__ void stage_chunk(const float* __restrict__ B, int k0, int rows,
                                            float* __restrict__ Bc, int tid) {
    const int n4 = rows * (DIM / 4);
    const float4* Bg = (const float4*)B + (size_t)k0 * (DIM / 4);
    float4* Bc4 = (float4*)Bc;
    for (int i = tid; i < n4; i += BLK) Bc4[i] = Bg[i];
}

__device__ __forceinline__ void init_acc_bias(float acc[4][8], const float* __restrict__ b, int ct) {
    float4 bb0 = *(const float4*)&b[ct * 8];
    float4 bb1 = *(const float4*)&b[ct * 8 + 4];
#pragma unroll
    for (int i = 0; i < 4; ++i) {
        acc[i][0] = bb0.x; acc[i][1] = bb0.y; acc[i][2] = bb0.z; acc[i][3] = bb0.w;
        acc[i][4] = bb1.x; acc[i][5] = bb1.y; acc[i][6] = bb1.z; acc[i][7] = bb1.w;
    }
}

template <int KPAD>
__device__ __forceinline__ void gemm_tile(const float* __restrict__ A_lds, int lda,
                                          const float* __restrict__ Bglob,
                                          float* __restrict__ Bc,
                                          float acc[4][8], int rt, int ct, int tid) {
    for (int k0 = 0; k0 < KPAD; k0 += 32) {
        __syncthreads();
        stage_chunk(Bglob, k0, 32, Bc, tid);
        __syncthreads();
#pragma unroll 2
        for (int k4 = 0; k4 < 8; ++k4) {
            float4 av[4];
#pragma unroll
            for (int i = 0; i < 4; ++i)
                av[i] = *(const float4*)&A_lds[(rt * 4 + i) * lda + k0 + k4 * 4];
#pragma unroll
            for (int kk = 0; kk < 4; ++kk) {
                const float* bp = &Bc[(k4 * 4 + kk) * DIM + ct * 8];
                float4 b0 = *(const float4*)bp;
                float4 b1 = *(const float4*)(bp + 4);
#pragma unroll
                for (int i = 0; i < 4; ++i) {
                    float a = ((const float*)&av[i])[kk];
                    acc[i][0] = fmaf(a, b0.x, acc[i][0]);
                    acc[i][1] = fmaf(a, b0.y, acc[i][1]);
                    acc[i][2] = fmaf(a, b0.z, acc[i][2]);
                    acc[i][3] = fmaf(a, b0.w, acc[i][3]);
                    acc[i][4] = fmaf(a, b1.x, acc[i][4]);
                    acc[i][5] = fmaf(a, b1.y, acc[i][5]);
                    acc[i][6] = fmaf(a, b1.z, acc[i][6]);
                    acc[i][7] = fmaf(a, b1.w, acc[i][7]);
                }
            }
        }
    }
}

template <int NK2>
__device__ __forceinline__ void gemm1_direct(const float* const (&frow)[4], int k2base,
                                             const float* __restrict__ Bc,
                                             float acc[4][8], int ct) {
#pragma unroll 4
    for (int k2 = 0; k2 < NK2; ++k2) {
        float2 a2[4];
#pragma unroll
        for (int i = 0; i < 4; ++i)
            a2[i] = *(const float2*)(frow[i] + (k2base + k2) * 2);
#pragma unroll
        for (int kk = 0; kk < 2; ++kk) {
            const float* bp = &Bc[(k2 * 2 + kk) * DIM + ct * 8];
            float4 b0 = *(const float4*)bp;
            float4 b1 = *(const float4*)(bp + 4);
#pragma unroll
            for (int i = 0; i < 4; ++i) {
                float a = kk ? a2[i].y : a2[i].x;
                acc[i][0] = fmaf(a, b0.x, acc[i][0]);
                acc[i][1] = fmaf(a, b0.y, acc[i][1]);
                acc[i][2] = fmaf(a, b0.z, acc[i][2]);
                acc[i][3] = fmaf(a, b0.w, acc[i][3]);
                acc[i][4] = fmaf(a, b1.x, acc[i][4]);
                acc[i][5] = fmaf(a, b1.y, acc[i][5]);
                acc[i][6] = fmaf(a, b1.z, acc[i][6]);
                acc[i][7] = fmaf(a, b1.w, acc[i][7]);
            }
        }
    }
}

__global__ __launch_bounds__(BLK) void node_in2f_fb(const float* __restrict__ x,
                                                    const float* __restrict__ W,
                                                    float* __restrict__ h) {
    __shared__ float At[TROWS * LDA];
    __shared__ float Bc[32 * DIM];
    const int tid = threadIdx.x;
    const int rt = tid >> 4, ct = tid & 15;
    const int n0 = blockIdx.x * TROWS;
    for (int i = tid; i < TROWS * (DIM / 4); i += BLK) {
        int row = i >> 5, c4 = i & 31;
        *(float4*)&At[row * LDA + c4 * 4] = *(const float4*)&x[(size_t)(n0 + row) * DIM + c4 * 4];
    }
    float acc[4][8];
#pragma unroll
    for (int i = 0; i < 4; ++i)
#pragma unroll
        for (int j = 0; j < 8; ++j) acc[i][j] = 0.f;
    gemm_tile<DIM>(At, LDA, W, Bc, acc, rt, ct, tid);
#pragma unroll
    for (int i = 0; i < 4; ++i) {
        float* hp = &h[(size_t)(n0 + rt * 4 + i) * DIM + ct * 8];
        *(float4*)hp = make_float4(acc[i][0], acc[i][1], acc[i][2], acc[i][3]);
        *(float4*)(hp + 4) = make_float4(acc[i][4], acc[i][5], acc[i][6], acc[i][7]);
    }
}

__global__ __launch_bounds__(BLK) void node_out_fb(const float* __restrict__ agg,
                                                   const float* __restrict__ W_out,
                                                   const float* __restrict__ b_out,
                                                   const float* __restrict__ W_lin,
                                                   const float* __restrict__ b_lin,
                                                   float* __restrict__ out) {
    __shared__ float At[TROWS * LDA];
    __shared__ float Bc[32 * DIM];
    const int tid = threadIdx.x;
    const int rt = tid >> 4, ct = tid & 15;
    const int n0 = blockIdx.x * TROWS;
    for (int i = tid; i < TROWS * (DIM / 4); i += BLK) {
        int row = i >> 5, c4 = i & 31;
        *(float4*)&At[row * LDA + c4 * 4] = *(const float4*)&agg[(size_t)(n0 + row) * DIM + c4 * 4];
    }
    float acc[4][8];
    init_acc_bias(acc, b_out, ct);
    gemm_tile<DIM>(At, LDA, W_out, Bc, acc, rt, ct, tid);
    __syncthreads();
#pragma unroll
    for (int i = 0; i < 4; ++i) {
        float* tp = &At[(rt * 4 + i) * LDA + ct * 8];
        *(float4*)tp = make_float4(ssp_f(acc[i][0]), ssp_f(acc[i][1]),
                                   ssp_f(acc[i][2]), ssp_f(acc[i][3]));
        *(float4*)(tp + 4) = make_float4(ssp_f(acc[i][4]), ssp_f(acc[i][5]),
                                         ssp_f(acc[i][6]), ssp_f(acc[i][7]));
    }
    init_acc_bias(acc, b_lin, ct);
    gemm_tile<DIM>(At, LDA, W_lin, Bc, acc, rt, ct, tid);
#pragma unroll
    for (int i = 0; i < 4; ++i) {
        float* op = &out[(size_t)(n0 + rt * 4 + i) * DIM + ct * 8];
        *(float4*)op = make_float4(acc[i][0], acc[i][1], acc[i][2], acc[i][3]);
        *(float4*)(op + 4) = make_float4(acc[i][4], acc[i][5], acc[i][6], acc[i][7]);
    }
}

__global__ __launch_bounds__(BLK) void edge_kernel_atomic(const float* __restrict__ f_ij,
                                                          const float* __restrict__ r_ij,
                                                          const int* __restrict__ ind_i,
                                                          const int* __restrict__ ind_j,
                                                          const float* __restrict__ W_f1,
                                                          const float* __restrict__ b_f1,
                                                          const float* __restrict__ W_f2,
                                                          const float* __restrict__ b_f2,
                                                          const float* __restrict__ h,
                                                          float* __restrict__ agg) {
    __shared__ float t1[TROWS * LDA];
    __shared__ float Bc[32 * DIM];
    const int tid = threadIdx.x;
    const int rt = tid >> 4, ct = tid & 15;
    const int e0 = blockIdx.x * TROWS;
    const float* frow[4];
#pragma unroll
    for (int i = 0; i < 4; ++i) frow[i] = f_ij + (size_t)(e0 + rt * 4 + i) * NB;
    float acc[4][8];
    init_acc_bias(acc, b_f1, ct);
    stage_chunk(W_f1, 0, 32, Bc, tid);
    __syncthreads();
    gemm1_direct<16>(frow, 0, Bc, acc, ct);
    __syncthreads();
    stage_chunk(W_f1, 32, 18, Bc, tid);
    __syncthreads();
    gemm1_direct<9>(frow, 16, Bc, acc, ct);
#pragma unroll
    for (int i = 0; i < 4; ++i) {
        float* tp = &t1[(rt * 4 + i) * LDA + ct * 8];
        *(float4*)tp = make_float4(ssp_f(acc[i][0]), ssp_f(acc[i][1]),
                                   ssp_f(acc[i][2]), ssp_f(acc[i][3]));
        *(float4*)(tp + 4) = make_float4(ssp_f(acc[i][4]), ssp_f(acc[i][5]),
                                         ssp_f(acc[i][6]), ssp_f(acc[i][7]));
    }
    init_acc_bias(acc, b_f2, ct);
    gemm_tile<DIM>(t1, LDA, W_f2, Bc, acc, rt, ct, tid);
#pragma unroll
    for (int i = 0; i < 4; ++i) {
        int e = e0 + rt * 4 + i;
        float r = r_ij[e];
        float C = (r < 5.0f) ? 0.5f * (cosf(r * PI_OVER_CUT) + 1.0f) : 0.0f;
        int nj = ind_j[e];
        int ni = ind_i[e];
        const float* hp = &h[(size_t)nj * DIM + ct * 8];
        float4 h0 = *(const float4*)hp;
        float4 h1 = *(const float4*)(hp + 4);
        float* ap = &agg[(size_t)ni * DIM + ct * 8];
        atomicAdd(ap + 0, h0.x * acc[i][0] * C);
        atomicAdd(ap + 1, h0.y * acc[i][1] * C);
        atomicAdd(ap + 2, h0.z * acc[i][2] * C);
        atomicAdd(ap + 3, h0.w * acc[i][3] * C);
        atomicAdd(ap + 4, h1.x * acc[i][4] * C);
        atomicAdd(ap + 5, h1.y * acc[i][5] * C);
        atomicAdd(ap + 6, h1.z * acc[i][6] * C);
        atomicAdd(ap + 7, h1.w * acc[i][7] * C);
    }
}

extern "C" void kernel_launch(void* const* d_in, const int* in_sizes, int n_in,
                              void* d_out, int out_size, void* d_ws, size_t ws_size,
                              hipStream_t stream) {
    const float* x      = (const float*)d_in[0];
    const float* r_ij   = (const float*)d_in[1];
    const float* f_ij   = (const float*)d_in[2];
    const int*   ind_i  = (const int*)d_in[3];
    const int*   ind_j  = (const int*)d_in[4];
    const float* W_in2f = (const float*)d_in[5];
    const float* W_f1   = (const float*)d_in[6];
    const float* b_f1   = (const float*)d_in[7];
    const float* W_f2   = (const float*)d_in[8];
    const float* b_f2   = (const float*)d_in[9];
    const float* W_out  = (const float*)d_in[10];
    const float* b_out  = (const float*)d_in[11];
    const float* W_lin  = (const float*)d_in[12];
    const float* b_lin  = (const float*)d_in[13];
    float* out = (float*)d_out;

    char* ws = (char*)d_ws;
    size_t off = 0;
    auto alloc = [&](size_t bytes) {
        char* p = ws + off;
        off = (off + bytes + 511) & ~(size_t)511;
        return p;
    };
    unsigned short* Wsplit = (unsigned short*)alloc(WSPLIT_USHORTS * sizeof(unsigned short));
    float*  h      = (float*)alloc((size_t)N_NODES_C * DIM * sizeof(float));
    float*  agg    = (float*)alloc((size_t)N_NODES_C * DIM * sizeof(float));
    __half* msg    = (__half*)alloc((size_t)N_EDGES_C * DIM * sizeof(__half));
    int*    pos    = (int*)alloc((size_t)N_EDGES_C * sizeof(int));
    int*    cnt    = (int*)alloc((size_t)N_NODES_C * sizeof(int));
    int*    startA = (int*)alloc((size_t)N_NODES_C * sizeof(int));
    int*    cursor = (int*)alloc((size_t)N_NODES_C * sizeof(int));
    int*    bsum   = (int*)alloc((size_t)NSCAN_BLK * sizeof(int));
    const bool have_ws = (off <= ws_size);

    if (have_ws) {
        split5_kernel<<<(18 * 4096 + BLK - 1) / BLK, BLK, 0, stream>>>(
            W_in2f, W_f1, W_f2, W_out, W_lin, Wsplit);

        node_in2f_mfma<<<N_NODES_C / TROWS, BLK, 0, stream>>>(x, Wsplit, h);

        hipMemsetAsync(cnt, 0, (size_t)N_NODES_C * sizeof(int), stream);
        hist_kernel<<<(N_EDGES_C + BLK - 1) / BLK, BLK, 0, stream>>>(ind_i, cnt);
        scan1_kernel<<<NSCAN_BLK, BLK, 0, stream>>>(cnt, startA, bsum);
        scan2_kernel<<<1, BLK, 0, stream>>>(bsum);
        scan3_kernel<<<NSCAN_BLK, BLK, 0, stream>>>(startA, cursor, bsum);
        place_kernel<<<(N_EDGES_C + BLK - 1) / BLK, BLK, 0, stream>>>(ind_i, cursor, pos);

        edge_kernel_mfma<<<N_EDGES_C / TROWS, BLK, 0, stream>>>(
            f_ij, r_ij, ind_j, pos, Wsplit, b_f1, b_f2, h, msg);
        gather_kernel<<<(N_NODES_C + 3) / 4, BLK, 0, stream>>>(msg, startA, cnt, agg);

        node_out_mfma<<<N_NODES_C / TROWS, BLK, 0, stream>>>(agg, Wsplit, b_out, b_lin, out);
    } else {
        // minimal-workspace vector fallback (h + agg only)
        float* h2   = (float*)d_ws;
        float* agg2 = h2 + (size_t)N_NODES_C * DIM;
        node_in2f_fb<<<N_NODES_C / TROWS, BLK, 0, stream>>>(x, W_in2f, h2);
        hipMemsetAsync(agg2, 0, (size_t)N_NODES_C * DIM * sizeof(float), stream);
        edge_kernel_atomic<<<N_EDGES_C / TROWS, BLK, 0, stream>>>(
            f_ij, r_ij, ind_i, ind_j, W_f1, b_f1, W_f2, b_f2, h2, agg2);
        node_out_fb<<<N_NODES_C / TROWS, BLK, 0, stream>>>(agg2, W_out, b_out, W_lin, b_lin, out);
    }
}

// Round 13
// 298.411 us; speedup vs baseline: 1.4814x; 1.0335x over previous
//
#include <hip/hip_runtime.h>
#include <hip/hip_fp16.h>

#define N_NODES_C 40000
#define N_EDGES_C 640000
#define DIM 128
#define NB 50
#define LDA 132       // f32 transpose-buffer leading dim (528B rows: 16B-aligned)
#define BLK 256
#define TROWS 64
#define LOG2_C 0.6931471805599453f
#define PI_OVER_CUT 0.6283185307179586f  // pi/5
#define NSCAN_BLK 157  // ceil(40000/256)

typedef __attribute__((ext_vector_type(8))) short s8v;   // 8 bf16 = A/B frag of 16x16x32
typedef __attribute__((ext_vector_type(4))) float f4v;   // C/D frag

#define MFMA_BF16 __builtin_amdgcn_mfma_f32_16x16x32_bf16

// Wsplit segment offsets (ushort units). Layout per weight: [nc][128 col][40], k at col*40+k.
#define SEG_IN2F_H 0
#define SEG_IN2F_L 20480
#define SEG_F1_H   40960
#define SEG_F1_L   51200
#define SEG_F2_H   61440
#define SEG_F2_L   81920
#define SEG_OUT_H  102400
#define SEG_OUT_L  122880
#define SEG_LIN_H  143360
#define SEG_LIN_L  163840
#define WSPLIT_USHORTS 184320

__device__ __forceinline__ unsigned short f2bf(float x) {   // RNE (pre-split kernel only)
    unsigned int u = __float_as_uint(x);
    u += 0x7fffu + ((u >> 16) & 1u);
    return (unsigned short)(u >> 16);
}
__device__ __forceinline__ float bf2f(unsigned short h) {
    return __uint_as_float(((unsigned int)h) << 16);
}
__device__ __forceinline__ float ssp_f(float t) {
    float e = __expf(-fabsf(t));
    return fmaxf(t, 0.0f) + __logf(1.0f + e) - LOG2_C;
}
// truncation split of 8 f32 -> bf16 hi/lo frags (residual exact)
__device__ __forceinline__ void split8t(const float* av, s8v& Ah, s8v& Al) {
#pragma unroll
    for (int j = 0; j < 8; j += 2) {
        unsigned int u0 = __float_as_uint(av[j]);
        unsigned int u1 = __float_as_uint(av[j + 1]);
        float h0 = __uint_as_float(u0 & 0xffff0000u);
        float h1 = __uint_as_float(u1 & 0xffff0000u);
        unsigned int r0 = __float_as_uint(av[j] - h0);
        unsigned int r1 = __float_as_uint(av[j + 1] - h1);
        ((unsigned int*)&Ah)[j >> 1] = __builtin_amdgcn_perm(u1, u0, 0x07060302);
        ((unsigned int*)&Al)[j >> 1] = __builtin_amdgcn_perm(r1, r0, 0x07060302);
    }
}
__device__ __forceinline__ void f2x4_to_split(const float2 v[4], s8v& Ah, s8v& Al) {
    float av[8] = {v[0].x, v[0].y, v[1].x, v[1].y, v[2].x, v[2].y, v[3].x, v[3].y};
    split8t(av, Ah, Al);
}
__device__ __forceinline__ void loadB4(const unsigned short* __restrict__ p, s8v B[4]) {
#pragma unroll
    for (int t = 0; t < 4; ++t) B[t] = *(const s8v*)(p + t * 640);
}
// first half: Ah x Bl term (8 MFMAs)
__device__ __forceinline__ void mfma8_half(const s8v B[4], const s8v& A0, const s8v& A1,
                                           f4v acc0[4], f4v acc1[4]) {
#pragma unroll
    for (int t = 0; t < 4; ++t) {
        acc0[t] = MFMA_BF16(A0, B[t], acc0[t], 0, 0, 0);
        acc1[t] = MFMA_BF16(A1, B[t], acc1[t], 0, 0, 0);
    }
}
// second half: Al x Bh + Ah x Bh terms (16 MFMAs)
__device__ __forceinline__ void mfma16_half(const s8v B[4], const s8v& Ah0, const s8v& Al0,
                                            const s8v& Ah1, const s8v& Al1,
                                            f4v acc0[4], f4v acc1[4]) {
#pragma unroll
    for (int t = 0; t < 4; ++t) {
        acc0[t] = MFMA_BF16(Al0, B[t], acc0[t], 0, 0, 0);
        acc0[t] = MFMA_BF16(Ah0, B[t], acc0[t], 0, 0, 0);
        acc1[t] = MFMA_BF16(Al1, B[t], acc1[t], 0, 0, 0);
        acc1[t] = MFMA_BF16(Ah1, B[t], acc1[t], 0, 0, 0);
    }
}
// old single-buffer combo (node_in2f + fallback-adjacent uses)
__device__ __forceinline__ void mfma4x2(const unsigned short* __restrict__ bh,
                                        const unsigned short* __restrict__ bl,
                                        const s8v& Ah0, const s8v& Al0,
                                        const s8v& Ah1, const s8v& Al1,
                                        f4v acc0[4], f4v acc1[4]) {
    s8v B[4];
    loadB4(bl, B);
    mfma8_half(B, Ah0, Ah1, acc0, acc1);
    loadB4(bh, B);
    mfma16_half(B, Ah0, Al0, Ah1, Al1, acc0, acc1);
}
__device__ __forceinline__ void init_acc_cols(f4v acc0[4], f4v acc1[4],
                                              const float* __restrict__ b, int colbase, int lr) {
#pragma unroll
    for (int t = 0; t < 4; ++t) {
        float bv = b[colbase + t * 16 + lr];
        acc0[t] = (f4v){bv, bv, bv, bv};
        acc1[t] = (f4v){bv, bv, bv, bv};
    }
}
// 4-kc GEMM: A-frags pre-split in LDS (t1h/t1l rows rowA0/rowA1), B ping-pong from Ws.
__device__ __forceinline__ void gemm_lds_ws(const unsigned short* __restrict__ t1h,
                                            const unsigned short* __restrict__ t1l,
                                            int rowA0, int rowA1, int lk,
                                            const unsigned short* __restrict__ bh,
                                            const unsigned short* __restrict__ bl,
                                            f4v acc0[4], f4v acc1[4]) {
    s8v BlA[4], BhA[4], BlB[4], BhB[4];
    loadB4(bl, BlA);
    loadB4(bh, BhA);
#define KC_STEP(K, BL, BH, BLN, BHN, LOADNEXT)                                 \
    {                                                                          \
        s8v Ah0 = *(const s8v*)&t1h[rowA0 * 136 + (K) * 32 + lk * 8];          \
        s8v Al0 = *(const s8v*)&t1l[rowA0 * 136 + (K) * 32 + lk * 8];          \
        s8v Ah1 = *(const s8v*)&t1h[rowA1 * 136 + (K) * 32 + lk * 8];          \
        s8v Al1 = *(const s8v*)&t1l[rowA1 * 136 + (K) * 32 + lk * 8];          \
        mfma8_half(BL, Ah0, Ah1, acc0, acc1);                                  \
        if (LOADNEXT) loadB4(bl + ((K) + 1) * 5120, BLN);                      \
        mfma16_half(BH, Ah0, Al0, Ah1, Al1, acc0, acc1);                       \
        if (LOADNEXT) loadB4(bh + ((K) + 1) * 5120, BHN);                      \
    }
    KC_STEP(0, BlA, BhA, BlB, BhB, true)
    KC_STEP(1, BlB, BhB, BlA, BhA, true)
    KC_STEP(2, BlA, BhA, BlB, BhB, true)
    KC_STEP(3, BlB, BhB, BlA, BhA, false)
#undef KC_STEP
}
// ssp + truncation-split of both acc tiles into t1h/t1l
__device__ __forceinline__ void store_t1_ssp(const f4v acc0[4], const f4v acc1[4],
                                             unsigned short* __restrict__ t1h,
                                             unsigned short* __restrict__ t1l,
                                             int rpair, int colbase, int lk, int lr) {
#pragma unroll
    for (int t = 0; t < 4; ++t)
#pragma unroll
        for (int r = 0; r < 4; ++r) {
            int col = colbase + t * 16 + lr;
            float v = ssp_f(acc0[t][r]);
            unsigned int u = __float_as_uint(v);
            float hf = __uint_as_float(u & 0xffff0000u);
            int idx = (rpair * 32 + lk * 4 + r) * 136 + col;
            t1h[idx] = (unsigned short)(u >> 16);
            t1l[idx] = (unsigned short)(__float_as_uint(v - hf) >> 16);
            v = ssp_f(acc1[t][r]);
            u = __float_as_uint(v);
            hf = __uint_as_float(u & 0xffff0000u);
            idx = (rpair * 32 + 16 + lk * 4 + r) * 136 + col;
            t1h[idx] = (unsigned short)(u >> 16);
            t1l[idx] = (unsigned short)(__float_as_uint(v - hf) >> 16);
        }
}

// ---------------- weight pre-split (once per launch) ----------------
__global__ __launch_bounds__(BLK) void split5_kernel(const float* __restrict__ Wa,
                                                     const float* __restrict__ Wb,
                                                     const float* __restrict__ Wc,
                                                     const float* __restrict__ Wd,
                                                     const float* __restrict__ We,
                                                     unsigned short* __restrict__ Ws) {
    int i = blockIdx.x * BLK + threadIdx.x;
    if (i >= 18 * 4096) return;
    int chunk = i >> 12, r = i & 4095, k = r & 31, col = r >> 5;
    const float* W; int Kr, ck, hb, lb;
    if (chunk < 4)       { W = Wa; Kr = 128; ck = chunk;      hb = SEG_IN2F_H; lb = SEG_IN2F_L; }
    else if (chunk < 6)  { W = Wb; Kr = 50;  ck = chunk - 4;  hb = SEG_F1_H;   lb = SEG_F1_L; }
    else if (chunk < 10) { W = Wc; Kr = 128; ck = chunk - 6;  hb = SEG_F2_H;   lb = SEG_F2_L; }
    else if (chunk < 14) { W = Wd; Kr = 128; ck = chunk - 10; hb = SEG_OUT_H;  lb = SEG_OUT_L; }
    else                 { W = We; Kr = 128; ck = chunk - 14; hb = SEG_LIN_H;  lb = SEG_LIN_L; }
    int krow = ck * 32 + k;
    float v = (krow < Kr) ? W[(size_t)krow * DIM + col] : 0.f;
    unsigned short h16 = f2bf(v);
    int o = ck * 5120 + col * 40 + k;
    Ws[hb + o] = h16;
    Ws[lb + o] = f2bf(v - bf2f(h16));
}

// ---------------- h = x @ W_in2f  (MFMA, no LDS, row-pair x col-half split) ----------------
__global__ __launch_bounds__(BLK, 4) void node_in2f_mfma(const float* __restrict__ x,
                                                         const unsigned short* __restrict__ Ws,
                                                         float* __restrict__ h) {
    const int tid = threadIdx.x;
    const int w = tid >> 6, l = tid & 63, lr = l & 15, lk = l >> 4;
    const int rpair = w & 1, colbase = (w >> 1) * 64;
    const int n0 = blockIdx.x * TROWS;
    const int rowA0 = rpair * 32 + lr, rowA1 = rowA0 + 16;
    const float* xr0 = x + (size_t)(n0 + rowA0) * DIM;
    const float* xr1 = x + (size_t)(n0 + rowA1) * DIM;

    f4v acc0[4], acc1[4];
#pragma unroll
    for (int t = 0; t < 4; ++t) {
        acc0[t] = (f4v){0.f, 0.f, 0.f, 0.f};
        acc1[t] = (f4v){0.f, 0.f, 0.f, 0.f};
    }
#pragma unroll
    for (int kc = 0; kc < 4; ++kc) {
        const float* ap0 = xr0 + kc * 32 + lk * 8;
        const float* ap1 = xr1 + kc * 32 + lk * 8;
        float4 a0 = *(const float4*)ap0, a1 = *(const float4*)(ap0 + 4);
        float4 b0 = *(const float4*)ap1, b1 = *(const float4*)(ap1 + 4);
        float av0[8] = {a0.x, a0.y, a0.z, a0.w, a1.x, a1.y, a1.z, a1.w};
        float av1[8] = {b0.x, b0.y, b0.z, b0.w, b1.x, b1.y, b1.z, b1.w};
        s8v Ah0, Al0, Ah1, Al1;
        split8t(av0, Ah0, Al0);
        split8t(av1, Ah1, Al1);
        const int bo = kc * 5120 + (colbase + lr) * 40 + lk * 8;
        mfma4x2(Ws + SEG_IN2F_H + bo, Ws + SEG_IN2F_L + bo, Ah0, Al0, Ah1, Al1, acc0, acc1);
    }
#pragma unroll
    for (int t = 0; t < 4; ++t)
#pragma unroll
        for (int r = 0; r < 4; ++r) {
            int col = colbase + t * 16 + lr;
            h[(size_t)(n0 + rpair * 32 + lk * 4 + r) * DIM + col] = acc0[t][r];
            h[(size_t)(n0 + rpair * 32 + 16 + lk * 4 + r) * DIM + col] = acc1[t][r];
        }
}

// ---------------- CSR build ----------------
__global__ __launch_bounds__(BLK) void hist_kernel(const int* __restrict__ ind_i,
                                                   int* __restrict__ cnt) {
    int e = blockIdx.x * BLK + threadIdx.x;
    if (e < N_EDGES_C) atomicAdd(&cnt[ind_i[e]], 1);
}

__global__ __launch_bounds__(BLK) void scan1_kernel(const int* __restrict__ cnt,
                                                    int* __restrict__ excl,
                                                    int* __restrict__ bsum) {
    __shared__ int s[BLK];
    const int tid = threadIdx.x;
    const int idx = blockIdx.x * BLK + tid;
    int v = (idx < N_NODES_C) ? cnt[idx] : 0;
    s[tid] = v;
    __syncthreads();
    for (int off = 1; off < BLK; off <<= 1) {
        int t = (tid >= off) ? s[tid - off] : 0;
        __syncthreads();
        s[tid] += t;
        __syncthreads();
    }
    if (idx < N_NODES_C) excl[idx] = s[tid] - v;
    if (tid == BLK - 1) bsum[blockIdx.x] = s[tid];
}

__global__ __launch_bounds__(BLK) void scan2_kernel(int* __restrict__ bsum) {
    __shared__ int s[BLK];
    const int tid = threadIdx.x;
    int v = (tid < NSCAN_BLK) ? bsum[tid] : 0;
    s[tid] = v;
    __syncthreads();
    for (int off = 1; off < BLK; off <<= 1) {
        int t = (tid >= off) ? s[tid - off] : 0;
        __syncthreads();
        s[tid] += t;
        __syncthreads();
    }
    if (tid < NSCAN_BLK) bsum[tid] = s[tid] - v;  // exclusive
}

__global__ __launch_bounds__(BLK) void scan3_kernel(int* __restrict__ start,
                                                    int* __restrict__ cursor,
                                                    const int* __restrict__ bsum) {
    const int idx = blockIdx.x * BLK + threadIdx.x;
    if (idx < N_NODES_C) {
        int v = start[idx] + bsum[blockIdx.x];
        start[idx] = v;
        cursor[idx] = v;
    }
}

__global__ __launch_bounds__(BLK) void place_kernel(const int* __restrict__ ind_i,
                                                    int* __restrict__ cursor,
                                                    int* __restrict__ pos) {
    int e = blockIdx.x * BLK + threadIdx.x;
    if (e < N_EDGES_C) {
        int slot = atomicAdd(&cursor[ind_i[e]], 1);
        pos[e] = slot;
    }
}

// ---------------- Edge kernel: pipelined B, hoisted A, fp16 msg ----------------
// LDS (34816B): t1h[64][136] + t1l[64][136] ushort; alias tf f32[64][132] post-GEMM2.
__global__ __launch_bounds__(BLK, 4) void edge_kernel_mfma(const float* __restrict__ f_ij,
                                                           const float* __restrict__ r_ij,
                                                           const int* __restrict__ ind_j,
                                                           const int* __restrict__ pos,
                                                           const unsigned short* __restrict__ Ws,
                                                           const float* __restrict__ b_f1,
                                                           const float* __restrict__ b_f2,
                                                           const float* __restrict__ h,
                                                           __half* __restrict__ msg) {
    __shared__ __align__(16) char smem[34816];
    unsigned short* t1h = (unsigned short*)smem;          // [64][136]
    unsigned short* t1l = t1h + 64 * 136;
    float* tf = (float*)smem;                             // [64][132] alias (post-GEMM2)

    const int tid = threadIdx.x;
    const int w = tid >> 6, l = tid & 63, lr = l & 15, lk = l >> 4;
    const int rt = tid >> 4, ct = tid & 15;
    const int rpair = w & 1, colbase = (w >> 1) * 64;
    const int e0 = blockIdx.x * TROWS;  // 640000 % 64 == 0
    const int rowA0 = rpair * 32 + lr, rowA1 = rowA0 + 16;
    const int boff = (colbase + lr) * 40 + lk * 8;

    // ---- hoist ALL GEMM1 A-data (f_ij) loads to kernel start
    const float* fr0 = f_ij + (size_t)(e0 + rowA0) * NB;
    const float* fr1 = f_ij + (size_t)(e0 + rowA1) * NB;
    float2 fv[2][2][4];
#pragma unroll
    for (int kc = 0; kc < 2; ++kc)
#pragma unroll
        for (int ii = 0; ii < 4; ++ii) {
            int k = kc * 32 + lk * 8 + ii * 2;        // pairs never straddle 50 (even)
            fv[kc][0][ii] = (k < NB) ? *(const float2*)(fr0 + k) : make_float2(0.f, 0.f);
            fv[kc][1][ii] = (k < NB) ? *(const float2*)(fr1 + k) : make_float2(0.f, 0.f);
        }

    // ---- GEMM1 (2 kc, ping-pong B)
    f4v acc0[4], acc1[4];
    init_acc_cols(acc0, acc1, b_f1, colbase, lr);
    const unsigned short* f1h = Ws + SEG_F1_H + boff;
    const unsigned short* f1l = Ws + SEG_F1_L + boff;
    {
        s8v BlA[4], BhA[4], BlB[4], BhB[4];
        loadB4(f1l, BlA);
        loadB4(f1h, BhA);
        {
            s8v Ah0, Al0, Ah1, Al1;
            f2x4_to_split(fv[0][0], Ah0, Al0);
            f2x4_to_split(fv[0][1], Ah1, Al1);
            mfma8_half(BlA, Ah0, Ah1, acc0, acc1);
            loadB4(f1l + 5120, BlB);
            mfma16_half(BhA, Ah0, Al0, Ah1, Al1, acc0, acc1);
            loadB4(f1h + 5120, BhB);
        }
        {
            s8v Ah0, Al0, Ah1, Al1;
            f2x4_to_split(fv[1][0], Ah0, Al0);
            f2x4_to_split(fv[1][1], Ah1, Al1);
            mfma8_half(BlB, Ah0, Ah1, acc0, acc1);
            mfma16_half(BhB, Ah0, Al0, Ah1, Al1, acc0, acc1);
        }
    }
    // t1 = ssp(C1) split into LDS
    store_t1_ssp(acc0, acc1, t1h, t1l, rpair, colbase, lk, lr);
    // epilogue metadata loads (issue early; consumed after GEMM2)
    float rr4[4]; int nj4[4], ps4[4];
#pragma unroll
    for (int i = 0; i < 4; ++i) {
        int e = e0 + rt * 4 + i;
        rr4[i] = r_ij[e];
        nj4[i] = ind_j[e];
        ps4[i] = pos[e];
    }
    __syncthreads();

    // ---- GEMM2 (4 kc, pipelined)
    init_acc_cols(acc0, acc1, b_f2, colbase, lr);
    gemm_lds_ws(t1h, t1l, rowA0, rowA1, lk,
                Ws + SEG_F2_H + boff, Ws + SEG_F2_L + boff, acc0, acc1);

    // h-gather loads issued before the barrier (latency hides under barrier + tf writes)
    float4 hv[4][2];
#pragma unroll
    for (int i = 0; i < 4; ++i) {
        const float* hp = &h[(size_t)nj4[i] * DIM + ct * 8];
        hv[i][0] = *(const float4*)hp;
        hv[i][1] = *(const float4*)(hp + 4);
    }
    __syncthreads();   // all t1 reads done before tf overwrite
#pragma unroll
    for (int t = 0; t < 4; ++t)
#pragma unroll
        for (int r = 0; r < 4; ++r) {
            int col = colbase + t * 16 + lr;
            tf[(rpair * 32 + lk * 4 + r) * LDA + col] = acc0[t][r];
            tf[(rpair * 32 + 16 + lk * 4 + r) * LDA + col] = acc1[t][r];
        }
    __syncthreads();

    // ---- epilogue: cutoff, modulate, write fp16 msg row at CSR slot pos[e]
#pragma unroll
    for (int i = 0; i < 4; ++i) {
        float C = (rr4[i] < 5.0f) ? (0.5f * __cosf(rr4[i] * PI_OVER_CUT) + 0.5f) : 0.0f;
        const float* ep = &tf[(rt * 4 + i) * LDA + ct * 8];
        float4 a0 = *(const float4*)ep, a1 = *(const float4*)(ep + 4);
        float4 h0 = hv[i][0], h1 = hv[i][1];
        __half2 o0 = __floats2half2_rn(h0.x * a0.x * C, h0.y * a0.y * C);
        __half2 o1 = __floats2half2_rn(h0.z * a0.z * C, h0.w * a0.w * C);
        __half2 o2 = __floats2half2_rn(h1.x * a1.x * C, h1.y * a1.y * C);
        __half2 o3 = __floats2half2_rn(h1.z * a1.z * C, h1.w * a1.w * C);
        __half* mp = &msg[(size_t)ps4[i] * DIM + ct * 8];   // 16B-aligned
        *(uint4*)mp = make_uint4(*(unsigned int*)&o0, *(unsigned int*)&o1,
                                 *(unsigned int*)&o2, *(unsigned int*)&o3);
    }
}

// ---------------- Fused: gather CSR msg -> agg(LDS, split) -> out MLP ----------------
__global__ __launch_bounds__(BLK, 4) void node_out_fused(const __half* __restrict__ msg,
                                                         const int* __restrict__ start,
                                                         const int* __restrict__ cnt,
                                                         const unsigned short* __restrict__ Ws,
                                                         const float* __restrict__ b_out,
                                                         const float* __restrict__ b_lin,
                                                         float* __restrict__ out) {
    __shared__ __align__(16) char smem[34816];
    unsigned short* t1h = (unsigned short*)smem;
    unsigned short* t1l = t1h + 64 * 136;

    const int tid = threadIdx.x;
    const int w = tid >> 6, l = tid & 63, lr = l & 15, lk = l >> 4;
    const int rpair = w & 1, colbase = (w >> 1) * 64;
    const int n0 = blockIdx.x * TROWS;
    const int rowA0 = rpair * 32 + lr, rowA1 = rowA0 + 16;
    const int boff = (colbase + lr) * 40 + lk * 8;

    // ---- phase A: gather. 16 lane-quarters x 4 nodes each; lane16 owns 8 cols.
    const int q = tid >> 4, l16 = tid & 15;
#pragma unroll
    for (int i = 0; i < 4; ++i) {
        int nrow = q * 4 + i;
        int node = n0 + nrow;
        int s = start[node];
        int d = cnt[node];
        float a[8] = {0.f, 0.f, 0.f, 0.f, 0.f, 0.f, 0.f, 0.f};
        const __half* bp = msg + (size_t)s * DIM + l16 * 8;
        for (int k = 0; k < d; ++k) {
            uint4 v = *(const uint4*)(bp + (size_t)k * DIM);
            const __half2* hp2 = (const __half2*)&v;
#pragma unroll
            for (int j = 0; j < 4; ++j) {
                float2 f = __half22float2(hp2[j]);
                a[j * 2] += f.x;
                a[j * 2 + 1] += f.y;
            }
        }
        s8v Ah, Al;
        split8t(a, Ah, Al);
        *(s8v*)&t1h[nrow * 136 + l16 * 8] = Ah;
        *(s8v*)&t1l[nrow * 136 + l16 * 8] = Al;
    }
    __syncthreads();

    // ---- GEMM_out: ssp(agg @ W_out + b_out)
    f4v acc0[4], acc1[4];
    init_acc_cols(acc0, acc1, b_out, colbase, lr);
    gemm_lds_ws(t1h, t1l, rowA0, rowA1, lk,
                Ws + SEG_OUT_H + boff, Ws + SEG_OUT_L + boff, acc0, acc1);
    __syncthreads();   // agg reads done before overwrite
    store_t1_ssp(acc0, acc1, t1h, t1l, rpair, colbase, lk, lr);
    __syncthreads();

    // ---- GEMM_lin: v @ W_lin + b_lin
    init_acc_cols(acc0, acc1, b_lin, colbase, lr);
    gemm_lds_ws(t1h, t1l, rowA0, rowA1, lk,
                Ws + SEG_LIN_H + boff, Ws + SEG_LIN_L + boff, acc0, acc1);
#pragma unroll
    for (int t = 0; t < 4; ++t)
#pragma unroll
        for (int r = 0; r < 4; ++r) {
            int col = colbase + t * 16 + lr;
            out[(size_t)(n0 + rpair * 32 + lk * 4 + r) * DIM + col] = acc0[t][r];
            out[(size_t)(n0 + rpair * 32 + 16 + lk * 4 + r) * DIM + col] = acc1[t][r];
        }
}

// ================= vector fallback path (only if workspace too small) =================
__device__ __forceinline__ void stage_chunk(const float* __restrict__ B, int k0, int rows,
                                            float* __restrict__ Bc, int tid) {
    const int n4 = rows * (DIM / 4);
    const float4* Bg = (const float4*)B + (size_t)k0 * (DIM / 4);
    float4* Bc4 = (float4*)Bc;
    for (int i = tid; i < n4; i += BLK) Bc4[i] = Bg[i];
}

__device__ __forceinline__ void init_acc_bias(float acc[4][8], const float* __restrict__ b, int ct) {
    float4 bb0 = *(const float4*)&b[ct * 8];
    float4 bb1 = *(const float4*)&b[ct * 8 + 4];
#pragma unroll
    for (int i = 0; i < 4; ++i) {
        acc[i][0] = bb0.x; acc[i][1] = bb0.y; acc[i][2] = bb0.z; acc[i][3] = bb0.w;
        acc[i][4] = bb1.x; acc[i][5] = bb1.y; acc[i][6] = bb1.z; acc[i][7] = bb1.w;
    }
}

template <int KPAD>
__device__ __forceinline__ void gemm_tile(const float* __restrict__ A_lds, int lda,
                                          const float* __restrict__ Bglob,
                                          float* __restrict__ Bc,
                                          float acc[4][8], int rt, int ct, int tid) {
    for (int k0 = 0; k0 < KPAD; k0 += 32) {
        __syncthreads();
        stage_chunk(Bglob, k0, 32, Bc, tid);
        __syncthreads();
#pragma unroll 2
        for (int k4 = 0; k4 < 8; ++k4) {
            float4 av[4];
#pragma unroll
            for (int i = 0; i < 4; ++i)
                av[i] = *(const float4*)&A_lds[(rt * 4 + i) * lda + k0 + k4 * 4];
#pragma unroll
            for (int kk = 0; kk < 4; ++kk) {
                const float* bp = &Bc[(k4 * 4 + kk) * DIM + ct * 8];
                float4 b0 = *(const float4*)bp;
                float4 b1 = *(const float4*)(bp + 4);
#pragma unroll
                for (int i = 0; i < 4; ++i) {
                    float a = ((const float*)&av[i])[kk];
                    acc[i][0] = fmaf(a, b0.x, acc[i][0]);
                    acc[i][1] = fmaf(a, b0.y, acc[i][1]);
                    acc[i][2] = fmaf(a, b0.z, acc[i][2]);
                    acc[i][3] = fmaf(a, b0.w, acc[i][3]);
                    acc[i][4] = fmaf(a, b1.x, acc[i][4]);
                    acc[i][5] = fmaf(a, b1.y, acc[i][5]);
                    acc[i][6] = fmaf(a, b1.z, acc[i][6]);
                    acc[i][7] = fmaf(a, b1.w, acc[i][7]);
                }
            }
        }
    }
}

template <int NK2>
__device__ __forceinline__ void gemm1_direct(const float* const (&frow)[4], int k2base,
                                             const float* __restrict__ Bc,
                                             float acc[4][8], int ct) {
#pragma unroll 4
    for (int k2 = 0; k2 < NK2; ++k2) {
        float2 a2[4];
#pragma unroll
        for (int i = 0; i < 4; ++i)
            a2[i] = *(const float2*)(frow[i] + (k2base + k2) * 2);
#pragma unroll
        for (int kk = 0; kk < 2; ++kk) {
            const float* bp = &Bc[(k2 * 2 + kk) * DIM + ct * 8];
            float4 b0 = *(const float4*)bp;
            float4 b1 = *(const float4*)(bp + 4);
#pragma unroll
            for (int i = 0; i < 4; ++i) {
                float a = kk ? a2[i].y : a2[i].x;
                acc[i][0] = fmaf(a, b0.x, acc[i][0]);
                acc[i][1] = fmaf(a, b0.y, acc[i][1]);
                acc[i][2] = fmaf(a, b0.z, acc[i][2]);
                acc[i][3] = fmaf(a, b0.w, acc[i][3]);
                acc[i][4] = fmaf(a, b1.x, acc[i][4]);
                acc[i][5] = fmaf(a, b1.y, acc[i][5]);
                acc[i][6] = fmaf(a, b1.z, acc[i][6]);
                acc[i][7] = fmaf(a, b1.w, acc[i][7]);
            }
        }
    }
}

__global__ __launch_bounds__(BLK) void node_in2f_fb(const float* __restrict__ x,
                                                    const float* __restrict__ W,
                                                    float* __restrict__ h) {
    __shared__ float At[TROWS * LDA];
    __shared__ float Bc[32 * DIM];
    const int tid = threadIdx.x;
    const int rt = tid >> 4, ct = tid & 15;
    const int n0 = blockIdx.x * TROWS;
    for (int i = tid; i < TROWS * (DIM / 4); i += BLK) {
        int row = i >> 5, c4 = i & 31;
        *(float4*)&At[row * LDA + c4 * 4] = *(const float4*)&x[(size_t)(n0 + row) * DIM + c4 * 4];
    }
    float acc[4][8];
#pragma unroll
    for (int i = 0; i < 4; ++i)
#pragma unroll
        for (int j = 0; j < 8; ++j) acc[i][j] = 0.f;
    gemm_tile<DIM>(At, LDA, W, Bc, acc, rt, ct, tid);
#pragma unroll
    for (int i = 0; i < 4; ++i) {
        float* hp = &h[(size_t)(n0 + rt * 4 + i) * DIM + ct * 8];
        *(float4*)hp = make_float4(acc[i][0], acc[i][1], acc[i][2], acc[i][3]);
        *(float4*)(hp + 4) = make_float4(acc[i][4], acc[i][5], acc[i][6], acc[i][7]);
    }
}

__global__ __launch_bounds__(BLK) void node_out_fb(const float* __restrict__ agg,
                                                   const float* __restrict__ W_out,
                                                   const float* __restrict__ b_out,
                                                   const float* __restrict__ W_lin,
                                                   const float* __restrict__ b_lin,
                                                   float* __restrict__ out) {
    __shared__ float At[TROWS * LDA];
    __shared__ float Bc[32 * DIM];
    const int tid = threadIdx.x;
    const int rt = tid >> 4, ct = tid & 15;
    const int n0 = blockIdx.x * TROWS;
    for (int i = tid; i < TROWS * (DIM / 4); i += BLK) {
        int row = i >> 5, c4 = i & 31;
        *(float4*)&At[row * LDA + c4 * 4] = *(const float4*)&agg[(size_t)(n0 + row) * DIM + c4 * 4];
    }
    float acc[4][8];
    init_acc_bias(acc, b_out, ct);
    gemm_tile<DIM>(At, LDA, W_out, Bc, acc, rt, ct, tid);
    __syncthreads();
#pragma unroll
    for (int i = 0; i < 4; ++i) {
        float* tp = &At[(rt * 4 + i) * LDA + ct * 8];
        *(float4*)tp = make_float4(ssp_f(acc[i][0]), ssp_f(acc[i][1]),
                                   ssp_f(acc[i][2]), ssp_f(acc[i][3]));
        *(float4*)(tp + 4) = make_float4(ssp_f(acc[i][4]), ssp_f(acc[i][5]),
                                         ssp_f(acc[i][6]), ssp_f(acc[i][7]));
    }
    init_acc_bias(acc, b_lin, ct);
    gemm_tile<DIM>(At, LDA, W_lin, Bc, acc, rt, ct, tid);
#pragma unroll
    for (int i = 0; i < 4; ++i) {
        float* op = &out[(size_t)(n0 + rt * 4 + i) * DIM + ct * 8];
        *(float4*)op = make_float4(acc[i][0], acc[i][1], acc[i][2], acc[i][3]);
        *(float4*)(op + 4) = make_float4(acc[i][4], acc[i][5], acc[i][6], acc[i][7]);
    }
}

__global__ __launch_bounds__(BLK) void edge_kernel_atomic(const float* __restrict__ f_ij,
                                                          const float* __restrict__ r_ij,
                                                          const int* __restrict__ ind_i,
                                                          const int* __restrict__ ind_j,
                                                          const float* __restrict__ W_f1,
                                                          const float* __restrict__ b_f1,
                                                          const float* __restrict__ W_f2,
                                                          const float* __restrict__ b_f2,
                                                          const float* __restrict__ h,
                                                          float* __restrict__ agg) {
    __shared__ float t1[TROWS * LDA];
    __shared__ float Bc[32 * DIM];
    const int tid = threadIdx.x;
    const int rt = tid >> 4, ct = tid & 15;
    const int e0 = blockIdx.x * TROWS;
    const float* frow[4];
#pragma unroll
    for (int i = 0; i < 4; ++i) frow[i] = f_ij + (size_t)(e0 + rt * 4 + i) * NB;
    float acc[4][8];
    init_acc_bias(acc, b_f1, ct);
    stage_chunk(W_f1, 0, 32, Bc, tid);
    __syncthreads();
    gemm1_direct<16>(frow, 0, Bc, acc, ct);
    __syncthreads();
    stage_chunk(W_f1, 32, 18, Bc, tid);
    __syncthreads();
    gemm1_direct<9>(frow, 16, Bc, acc, ct);
#pragma unroll
    for (int i = 0; i < 4; ++i) {
        float* tp = &t1[(rt * 4 + i) * LDA + ct * 8];
        *(float4*)tp = make_float4(ssp_f(acc[i][0]), ssp_f(acc[i][1]),
                                   ssp_f(acc[i][2]), ssp_f(acc[i][3]));
        *(float4*)(tp + 4) = make_float4(ssp_f(acc[i][4]), ssp_f(acc[i][5]),
                                         ssp_f(acc[i][6]), ssp_f(acc[i][7]));
    }
    init_acc_bias(acc, b_f2, ct);
    gemm_tile<DIM>(t1, LDA, W_f2, Bc, acc, rt, ct, tid);
#pragma unroll
    for (int i = 0; i < 4; ++i) {
        int e = e0 + rt * 4 + i;
        float r = r_ij[e];
        float C = (r < 5.0f) ? 0.5f * (cosf(r * PI_OVER_CUT) + 1.0f) : 0.0f;
        int nj = ind_j[e];
        int ni = ind_i[e];
        const float* hp = &h[(size_t)nj * DIM + ct * 8];
        float4 h0 = *(const float4*)hp;
        float4 h1 = *(const float4*)(hp + 4);
        float* ap = &agg[(size_t)ni * DIM + ct * 8];
        atomicAdd(ap + 0, h0.x * acc[i][0] * C);
        atomicAdd(ap + 1, h0.y * acc[i][1] * C);
        atomicAdd(ap + 2, h0.z * acc[i][2] * C);
        atomicAdd(ap + 3, h0.w * acc[i][3] * C);
        atomicAdd(ap + 4, h1.x * acc[i][4] * C);
        atomicAdd(ap + 5, h1.y * acc[i][5] * C);
        atomicAdd(ap + 6, h1.z * acc[i][6] * C);
        atomicAdd(ap + 7, h1.w * acc[i][7] * C);
    }
}

extern "C" void kernel_launch(void* const* d_in, const int* in_sizes, int n_in,
                              void* d_out, int out_size, void* d_ws, size_t ws_size,
                              hipStream_t stream) {
    const float* x      = (const float*)d_in[0];
    const float* r_ij   = (const float*)d_in[1];
    const float* f_ij   = (const float*)d_in[2];
    const int*   ind_i  = (const int*)d_in[3];
    const int*   ind_j  = (const int*)d_in[4];
    const float* W_in2f = (const float*)d_in[5];
    const float* W_f1   = (const float*)d_in[6];
    const float* b_f1   = (const float*)d_in[7];
    const float* W_f2   = (const float*)d_in[8];
    const float* b_f2   = (const float*)d_in[9];
    const float* W_out  = (const float*)d_in[10];
    const float* b_out  = (const float*)d_in[11];
    const float* W_lin  = (const float*)d_in[12];
    const float* b_lin  = (const float*)d_in[13];
    float* out = (float*)d_out;

    char* ws = (char*)d_ws;
    size_t off = 0;
    auto alloc = [&](size_t bytes) {
        char* p = ws + off;
        off = (off + bytes + 511) & ~(size_t)511;
        return p;
    };
    unsigned short* Wsplit = (unsigned short*)alloc(WSPLIT_USHORTS * sizeof(unsigned short));
    float*  h      = (float*)alloc((size_t)N_NODES_C * DIM * sizeof(float));
    __half* msg    = (__half*)alloc((size_t)N_EDGES_C * DIM * sizeof(__half));
    int*    pos    = (int*)alloc((size_t)N_EDGES_C * sizeof(int));
    int*    cnt    = (int*)alloc((size_t)N_NODES_C * sizeof(int));
    int*    startA = (int*)alloc((size_t)N_NODES_C * sizeof(int));
    int*    cursor = (int*)alloc((size_t)N_NODES_C * sizeof(int));
    int*    bsum   = (int*)alloc((size_t)NSCAN_BLK * sizeof(int));
    const bool have_ws = (off <= ws_size);

    if (have_ws) {
        split5_kernel<<<(18 * 4096 + BLK - 1) / BLK, BLK, 0, stream>>>(
            W_in2f, W_f1, W_f2, W_out, W_lin, Wsplit);

        node_in2f_mfma<<<N_NODES_C / TROWS, BLK, 0, stream>>>(x, Wsplit, h);

        hipMemsetAsync(cnt, 0, (size_t)N_NODES_C * sizeof(int), stream);
        hist_kernel<<<(N_EDGES_C + BLK - 1) / BLK, BLK, 0, stream>>>(ind_i, cnt);
        scan1_kernel<<<NSCAN_BLK, BLK, 0, stream>>>(cnt, startA, bsum);
        scan2_kernel<<<1, BLK, 0, stream>>>(bsum);
        scan3_kernel<<<NSCAN_BLK, BLK, 0, stream>>>(startA, cursor, bsum);
        place_kernel<<<(N_EDGES_C + BLK - 1) / BLK, BLK, 0, stream>>>(ind_i, cursor, pos);

        edge_kernel_mfma<<<N_EDGES_C / TROWS, BLK, 0, stream>>>(
            f_ij, r_ij, ind_j, pos, Wsplit, b_f1, b_f2, h, msg);

        node_out_fused<<<N_NODES_C / TROWS, BLK, 0, stream>>>(
            msg, startA, cnt, Wsplit, b_out, b_lin, out);
    } else {
        // minimal-workspace vector fallback (h + agg only)
        float* h2   = (float*)d_ws;
        float* agg2 = h2 + (size_t)N_NODES_C * DIM;
        node_in2f_fb<<<N_NODES_C / TROWS, BLK, 0, stream>>>(x, W_in2f, h2);
        hipMemsetAsync(agg2, 0, (size_t)N_NODES_C * DIM * sizeof(float), stream);
        edge_kernel_atomic<<<N_EDGES_C / TROWS, BLK, 0, stream>>>(
            f_ij, r_ij, ind_i, ind_j, W_f1, b_f1, W_f2, b_f2, h2, agg2);
        node_out_fb<<<N_NODES_C / TROWS, BLK, 0, stream>>>(agg2, W_out, b_out, W_lin, b_lin, out);
    }
}